// Round 13
// baseline (257.964 us; speedup 1.0000x reference)
//
#include <hip/hip_runtime.h>
#include <hip/hip_fp16.h>

#define HH 128
#define WW 128
#define NPIX (HH*WW)
#define NB 8
#define NHEADS 6
#define HD 32
#define SCALE 0.17677669529663687f

typedef _Float16 h2 __attribute__((ext_vector_type(2)));
typedef __fp16 g2 __attribute__((ext_vector_type(2)));
typedef _Float16 f16x4 __attribute__((ext_vector_type(4)));
typedef _Float16 f16x8 __attribute__((ext_vector_type(8)));
typedef float f4 __attribute__((ext_vector_type(4)));

#define LDK 40    // na2d Vt padded stride
union U4 { g2 p2[2]; f16x4 v4; };

// ---------------- prep: WT[z][n][k] fp16 from W[z][k][n] fp32 ----------------
__global__ __launch_bounds__(512) void prep_wt(
    const float* __restrict__ Wq, const float* __restrict__ Wk,
    const float* __restrict__ Wv, _Float16* __restrict__ wt)
{
    int idx = blockIdx.x * 512 + threadIdx.x;      // 3*36864 total
    int mat = idx / 36864, rem = idx % 36864;
    int k = rem / 192, n = rem % 192;              // coalesced read over n
    const float* W = mat == 0 ? Wq : (mat == 1 ? Wk : Wv);
    wt[(size_t)mat * 36864 + (size_t)n * 192 + k] = (_Float16)W[(size_t)k * 192 + n];
}

__global__ __launch_bounds__(512) void prep_wo(
    const float* __restrict__ Wo, _Float16* __restrict__ woT)
{
    int idx = blockIdx.x * 512 + threadIdx.x;      // 36864
    int k = idx / 192, n = idx % 192;
    woT[(size_t)n * 192 + k] = (_Float16)Wo[(size_t)k * 192 + n];
}

// ---------------- MFMA projection v8: 256-thread / 64-pixel tile / 24KB LDS ----------------
// Same proven structure as v7 (stage A once swizzled; WT frags from L2; LDS output
// transpose; coalesced 16B stores) but 6 blocks/CU instead of 3: smaller barrier
// domains + 75% occupancy attack the latency-bound profile (VALUBusy 15%, VGPR 40).
__global__ __launch_bounds__(256) void proj_mfma(
    const float* __restrict__ x, const float* __restrict__ ctx,
    const _Float16* __restrict__ wt,
    const float* __restrict__ bq, const float* __restrict__ bk, const float* __restrict__ bv,
    _Float16* __restrict__ qh, _Float16* __restrict__ kh, _Float16* __restrict__ vh)
{
    int bid = blockIdx.x;             // 6144
    int xcd = bid & 7;
    int i = bid >> 3;                 // 0..767
    int z, xb;
    if (i < 256) { z = 0; xb = xcd * 256 + i; }
    else { int j = i - 256; z = 1 + (j & 1); xb = xcd * 256 + (j >> 1); }

    const float* A  = (z == 0) ? x : ctx;
    const _Float16* WT = wt + (size_t)z * 36864;
    const float* bias = (z == 0) ? bq : (z == 1 ? bk : bv);
    _Float16* outp = (z == 0) ? qh : (z == 1 ? kh : vh);
    float scale = (z == 0) ? SCALE : 1.f;

    __shared__ _Float16 Ts[64 * 192];   // 24KB, XOR-swizzled: idx = pix*192 + (off ^ ((pix&7)<<3))

    int t = threadIdx.x;
    int m0 = xb * 64;
    int b  = m0 / NPIX;
    int p0 = m0 % NPIX;
    const float* Ab = A + (size_t)b * 192 * NPIX + p0;

    int lane = t & 63;
    int wn   = t >> 6;        // 4 waves = 4 n-quarters of 48 channels
    int lq = lane & 15;
    int lk = lane >> 4;

    // ---- stage A tile once: coalesced fp32 reads (256B/wave), swizzled 8B LDS writes ----
    {
        int cq = t >> 6, pp = t & 63;
        int sw = (pp & 7) << 3;
        #pragma unroll
        for (int j = 0; j < 12; j++) {
            int c0 = cq * 48 + j * 4;
            float a0 = Ab[(size_t)(c0)     * NPIX + pp];
            float a1 = Ab[(size_t)(c0 + 1) * NPIX + pp];
            float a2 = Ab[(size_t)(c0 + 2) * NPIX + pp];
            float a3 = Ab[(size_t)(c0 + 3) * NPIX + pp];
            U4 u;
            u.p2[0] = __builtin_amdgcn_cvt_pkrtz(a0, a1);
            u.p2[1] = __builtin_amdgcn_cvt_pkrtz(a2, a3);
            *(f16x4*)&Ts[pp * 192 + (c0 ^ sw)] = u.v4;
        }
    }
    __syncthreads();

    // ---- MFMA loop: WT frags per k-step from L2, A frags from swizzled LDS ----
    f4 acc[12] = {};
    #pragma unroll
    for (int ks = 0; ks < 6; ks++) {
        f16x8 wf[3];
        #pragma unroll
        for (int ni = 0; ni < 3; ni++)
            wf[ni] = *(const f16x8*)&WT[(size_t)(wn * 48 + ni * 16 + lq) * 192 + ks * 32 + lk * 8];
        #pragma unroll
        for (int mi = 0; mi < 4; mi++) {
            int pix = mi * 16 + lq;
            f16x8 pfr = *(const f16x8*)&Ts[pix * 192 + ((ks * 32 + lk * 8) ^ ((pix & 7) << 3))];
            #pragma unroll
            for (int ni = 0; ni < 3; ni++)
                acc[mi * 3 + ni] = __builtin_amdgcn_mfma_f32_16x16x32_f16(wf[ni], pfr, acc[mi * 3 + ni], 0, 0, 0);
        }
    }
    __syncthreads();   // done reading A; reuse Ts for output transpose

    // ---- transpose: lane owns pixel, 4 consecutive channels -> swizzled 8B LDS writes ----
    #pragma unroll
    for (int mi = 0; mi < 4; mi++) {
        int pix = mi * 16 + lq;
        int sw = (pix & 7) << 3;
        #pragma unroll
        for (int ni = 0; ni < 3; ni++) {
            int n0 = wn * 48 + ni * 16 + lk * 4;
            f4 v = acc[mi * 3 + ni];
            f4 bb = *(const f4*)&bias[n0];
            U4 u;
            u.p2[0] = __builtin_amdgcn_cvt_pkrtz((v[0] + bb[0]) * scale, (v[1] + bb[1]) * scale);
            u.p2[1] = __builtin_amdgcn_cvt_pkrtz((v[2] + bb[2]) * scale, (v[3] + bb[3]) * scale);
            *(f16x4*)&Ts[pix * 192 + (n0 ^ sw)] = u.v4;
        }
    }
    __syncthreads();

    // ---- coalesced store: thread -> (pixel p2, 16B chunk qc); 6 heads x 16B ----
    {
        int p2 = t >> 2, qc = t & 3;
        int sw = (p2 & 7) << 3;
        #pragma unroll
        for (int g = 0; g < 6; g++) {
            f16x8 val = *(const f16x8*)&Ts[p2 * 192 + ((g * 32 + qc * 8) ^ sw)];
            *(f16x8*)(outp + ((size_t)(b * NHEADS + g) * NPIX + p0 + p2) * HD + qc * 8) = val;
        }
    }
}

// ---------------- MFMA neighborhood attention v2 (unchanged from R12) ----------------
#define NA2D_SMEM 68352          // 66560 (Vt) + 1764 (rpb) rounded

template<int K>
__device__ __forceinline__ void na2d_tile(
    const _Float16* __restrict__ qh, const _Float16* __restrict__ kh,
    const _Float16* __restrict__ vh, const float* __restrict__ rpb,
    _Float16* __restrict__ ah, char* smem, int b, int g_head, int hi, int ty, int tx)
{
    constexpr int NS = K / 2;
    constexpr int RW = 2 * K - 1;
    _Float16* Vt = (_Float16*)smem;
    float* rpbs = (float*)(smem + 66560);

    int t = threadIdx.x;
    size_t plane = (size_t)(b * NHEADS + g_head) * NPIX;
    int h0 = ty * 16, w0 = tx * 16;
    int rmin = min(max(h0 - NS, 0), HH - K);
    int rtop = min(max(h0 + 15 - NS, 0), HH - K);
    int rows_n = rtop + K - rmin;
    int cwin0 = min(max(w0 - NS, 0), WW - K);
    int ctop = min(max(w0 + 15 - NS, 0), WW - K);
    int cols_n = ctop + K - cwin0;

    for (int i = t; i < RW * RW; i += 512) rpbs[i] = rpb[(size_t)hi * RW * RW + i];

    int ntask = rows_n * 128;
    for (int idx = t; idx < ntask; idx += 512) {
        int row = idx >> 7;
        int key = (idx >> 2) & 31;
        int dc  = idx & 3;
        f16x8 vvv = {0,0,0,0,0,0,0,0};
        if (key < cols_n) {
            size_t pix = plane + (size_t)(rmin + row) * WW + (cwin0 + key);
            vvv = *(const f16x8*)&vh[pix * HD + dc * 8];
        }
        int m = 8 * ((key & 15) >> 2) + 4 * (key >> 4) + (key & 3);
        #pragma unroll
        for (int j = 0; j < 8; j++)
            Vt[row * 1280 + (dc * 8 + j) * LDK + m] = vvv[j];
    }
    __syncthreads();

    int lane = t & 63, wid = t >> 6;
    int lq = lane & 15, lg = lane >> 4;
    int wq = w0 + lq;
    int c0q = min(max(wq - NS, 0), WW - K);
    int klo = c0q - cwin0;
    int shiftc = cwin0 - wq + K - 1;
    f4 zf4 = {0.f, 0.f, 0.f, 0.f};

    #pragma unroll 1
    for (int qi = 0; qi < 2; qi++) {
        int qr = wid * 2 + qi;
        int h = h0 + qr;
        int r0q = min(max(h - NS, 0), HH - K);
        int row_base = r0q - rmin;
        f16x8 qf = *(const f16x8*)&qh[(plane + (size_t)h * WW + w0 + lq) * HD + lg * 8];
        f4 acc0 = zf4, acc1 = zf4;
        float lsum = 0.f;

        #pragma unroll 1
        for (int ki = 0; ki < K; ki++) {
            int row = row_base + ki;
            const _Float16* kgrow = kh + (plane + (size_t)(rmin + row) * WW + cwin0) * HD;
            f16x8 a0 = *(const f16x8*)&kgrow[(size_t)lq * HD + lg * 8];
            f16x8 a1 = *(const f16x8*)&kgrow[(size_t)(16 + lq) * HD + lg * 8];
            f4 s0 = __builtin_amdgcn_mfma_f32_16x16x32_f16(a0, qf, zf4, 0, 0, 0);
            f4 s1 = __builtin_amdgcn_mfma_f32_16x16x32_f16(a1, qf, zf4, 0, 0, 0);

            int rel_r = r0q + ki - h + K - 1;
            const float* rrow = rpbs + rel_r * RW;
            float pf[2][4];
            #pragma unroll
            for (int c = 0; c < 2; c++) {
                #pragma unroll
                for (int r = 0; r < 4; r++) {
                    int key_local = c * 16 + 4 * lg + r;
                    int rc = key_local + shiftc;
                    rc = min(max(rc, 0), RW - 1);
                    float biasv = rrow[rc];
                    bool valid = (unsigned)(key_local - klo) < (unsigned)K;
                    float sv = (c ? s1[r] : s0[r]) + biasv;
                    float pv = valid ? __expf(sv) : 0.f;
                    pf[c][r] = pv;
                    lsum += pv;
                }
            }
            union { g2 p[4]; f16x8 v; } P;
            P.p[0] = __builtin_amdgcn_cvt_pkrtz(pf[0][0], pf[0][1]);
            P.p[1] = __builtin_amdgcn_cvt_pkrtz(pf[0][2], pf[0][3]);
            P.p[2] = __builtin_amdgcn_cvt_pkrtz(pf[1][0], pf[1][1]);
            P.p[3] = __builtin_amdgcn_cvt_pkrtz(pf[1][2], pf[1][3]);

            const _Float16* vbase = &Vt[row * 1280 + lg * 8];
            f16x8 b0 = *(const f16x8*)&vbase[lq * LDK];
            f16x8 b1 = *(const f16x8*)&vbase[(16 + lq) * LDK];
            acc0 = __builtin_amdgcn_mfma_f32_16x16x32_f16(P.v, b0, acc0, 0, 0, 0);
            acc1 = __builtin_amdgcn_mfma_f32_16x16x32_f16(P.v, b1, acc1, 0, 0, 0);
        }

        lsum += __shfl_xor(lsum, 16);
        lsum += __shfl_xor(lsum, 32);
        float inv = 1.f / lsum;
        _Float16* obase = ah + (plane + (size_t)h * WW + w0) * HD;
        #pragma unroll
        for (int r = 0; r < 4; r++) {
            float ir = __shfl(inv, 4 * lg + r);
            obase[(4 * lg + r) * HD + lq]      = (_Float16)(acc0[r] * ir);
            obase[(4 * lg + r) * HD + lq + 16] = (_Float16)(acc1[r] * ir);
        }
    }
}

__global__ __launch_bounds__(512) void na2d_mfma(
    const _Float16* __restrict__ qh, const _Float16* __restrict__ kh,
    const _Float16* __restrict__ vh,
    const float* __restrict__ rpb0, const float* __restrict__ rpb1,
    const float* __restrict__ rpb2, _Float16* __restrict__ ah)
{
    extern __shared__ char smem[];
    int bid = blockIdx.x;
    int xcd = bid & 7;
    int i = bid >> 3;
    int phase = i >> 7;
    int j = i & 127;
    int lb = xcd * 128 + j;
    int bz = lb >> 6;
    int tile = lb & 63;
    int b = bz >> 1, hi = bz & 1;
    int ty = tile >> 3, tx = tile & 7;
    if (phase == 0)      na2d_tile<7>(qh, kh, vh, rpb0, ah, smem, b, 0 + hi, hi, ty, tx);
    else if (phase == 1) na2d_tile<9>(qh, kh, vh, rpb1, ah, smem, b, 2 + hi, hi, ty, tx);
    else                 na2d_tile<11>(qh, kh, vh, rpb2, ah, smem, b, 4 + hi, hi, ty, tx);
}

// ---------------- MFMA output projection (unchanged from R9-R12) ----------------
__global__ __launch_bounds__(512) void oproj_mfma(
    const _Float16* __restrict__ ah, const _Float16* __restrict__ woT,
    const float* __restrict__ bo, float* __restrict__ outp)
{
    int t = threadIdx.x;
    int m0 = blockIdx.x * 128;
    int b  = m0 / NPIX;
    int p0 = m0 % NPIX;

    int lane = t & 63;
    int wid  = t >> 6;
    int wm = wid & 1;
    int wn = wid >> 1;
    int lr = lane & 15;
    int lk = lane >> 4;

    f4 acc[4][3] = {};

    #pragma unroll
    for (int ks = 0; ks < 6; ks++) {
        const _Float16* abase = ah + (size_t)(b * NHEADS + ks) * NPIX * HD;
        f16x8 af[4], bf[3];
        #pragma unroll
        for (int mi = 0; mi < 4; mi++)
            af[mi] = *(const f16x8*)&abase[(size_t)(p0 + wm * 64 + mi * 16 + lr) * HD + lk * 8];
        #pragma unroll
        for (int ni = 0; ni < 3; ni++)
            bf[ni] = *(const f16x8*)&woT[(size_t)(wn * 48 + ni * 16 + lr) * 192 + ks * 32 + lk * 8];
        #pragma unroll
        for (int mi = 0; mi < 4; mi++)
            #pragma unroll
            for (int ni = 0; ni < 3; ni++)
                acc[mi][ni] = __builtin_amdgcn_mfma_f32_16x16x32_f16(af[mi], bf[ni], acc[mi][ni], 0, 0, 0);
    }

    #pragma unroll
    for (int ni = 0; ni < 3; ni++) {
        int n = wn * 48 + ni * 16 + lr;
        float bb = bo[n];
        float* obase = outp + ((size_t)b * 192 + n) * NPIX + p0 + wm * 64;
        #pragma unroll
        for (int mi = 0; mi < 4; mi++) {
            f4 v = acc[mi][ni];
            v[0] += bb; v[1] += bb; v[2] += bb; v[3] += bb;
            *(f4*)&obase[mi * 16 + lk * 4] = v;
        }
    }
}

extern "C" void kernel_launch(void* const* d_in, const int* in_sizes, int n_in,
                              void* d_out, int out_size, void* d_ws, size_t ws_size,
                              hipStream_t stream) {
    const float* x    = (const float*)d_in[0];
    const float* ctx  = (const float*)d_in[1];
    const float* Wq   = (const float*)d_in[2];
    const float* bq   = (const float*)d_in[3];
    const float* Wk   = (const float*)d_in[4];
    const float* bk   = (const float*)d_in[5];
    const float* Wv   = (const float*)d_in[6];
    const float* bv   = (const float*)d_in[7];
    const float* Wo   = (const float*)d_in[8];
    const float* bo   = (const float*)d_in[9];
    const float* rpb0 = (const float*)d_in[10];
    const float* rpb1 = (const float*)d_in[11];
    const float* rpb2 = (const float*)d_in[12];

    size_t N = (size_t)NB * NHEADS * NPIX * HD;   // 25,165,824 fp16 elements = 50.33MB
    _Float16* qh = (_Float16*)d_ws;
    _Float16* kh = qh + N;
    _Float16* vh = kh + N;
    _Float16* ah = vh + N;
    float* outp = (float*)d_out;

    // parking: WT fp16 in second half of d_out (dead until oproj); woT in qh (dead after na2d)
    _Float16* wt  = (_Float16*)d_out + N;
    _Float16* woT = qh;

    (void)hipFuncSetAttribute((const void*)na2d_mfma,
                              hipFuncAttributeMaxDynamicSharedMemorySize, NA2D_SMEM);

    prep_wt<<<216, 512, 0, stream>>>(Wq, Wk, Wv, wt);
    proj_mfma<<<6144, 256, 0, stream>>>(x, ctx, wt, bq, bk, bv, qh, kh, vh);
    na2d_mfma<<<3072, 512, NA2D_SMEM, stream>>>(qh, kh, vh, rpb0, rpb1, rpb2, ah);
    prep_wo<<<72, 512, 0, stream>>>(Wo, woT);
    oproj_mfma<<<1024, 512, 0, stream>>>(ah, woT, bo, outp);
}

// Round 14
// 253.895 us; speedup vs baseline: 1.0160x; 1.0160x over previous
//
#include <hip/hip_runtime.h>
#include <hip/hip_fp16.h>

#define HH 128
#define WW 128
#define NPIX (HH*WW)
#define NB 8
#define NHEADS 6
#define HD 32
#define SCALE 0.17677669529663687f

typedef _Float16 h2 __attribute__((ext_vector_type(2)));
typedef __fp16 g2 __attribute__((ext_vector_type(2)));
typedef _Float16 f16x4 __attribute__((ext_vector_type(4)));
typedef _Float16 f16x8 __attribute__((ext_vector_type(8)));
typedef float f4 __attribute__((ext_vector_type(4)));

#define LDK 40    // na2d Vt padded stride
union U4 { g2 p2[2]; f16x4 v4; };

// ---------------- prep: WT[z][n][k] fp16 from W[z][k][n] fp32 ----------------
__global__ __launch_bounds__(512) void prep_wt(
    const float* __restrict__ Wq, const float* __restrict__ Wk,
    const float* __restrict__ Wv, _Float16* __restrict__ wt)
{
    int idx = blockIdx.x * 512 + threadIdx.x;      // 3*36864 total
    int mat = idx / 36864, rem = idx % 36864;
    int k = rem / 192, n = rem % 192;              // coalesced read over n
    const float* W = mat == 0 ? Wq : (mat == 1 ? Wk : Wv);
    wt[(size_t)mat * 36864 + (size_t)n * 192 + k] = (_Float16)W[(size_t)k * 192 + n];
}

__global__ __launch_bounds__(512) void prep_wo(
    const float* __restrict__ Wo, _Float16* __restrict__ woT)
{
    int idx = blockIdx.x * 512 + threadIdx.x;      // 36864
    int k = idx / 192, n = idx % 192;
    woT[(size_t)n * 192 + k] = (_Float16)Wo[(size_t)k * 192 + n];
}

// ---------------- MFMA projection v9: forced-wide staging + k/v fusion ----------------
// 2048 blocks x 512 threads: per XCD 128 q-tiles then 128 kv-tiles (ctx staged ONCE,
// k-loop then v-loop reuse the LDS A-tile; only one barrier in the kv path).
// Staging: explicit 32/16-load batches with sched_barrier(0) so all loads of a batch
// are in flight before any cvt consumes them (~2 L2 round-trips instead of ~6).
__global__ __launch_bounds__(512, 4) void proj_mfma(
    const float* __restrict__ x, const float* __restrict__ ctx,
    const _Float16* __restrict__ wt,
    const float* __restrict__ bq, const float* __restrict__ bk, const float* __restrict__ bv,
    _Float16* __restrict__ qh, _Float16* __restrict__ kh, _Float16* __restrict__ vh)
{
    int bid = blockIdx.x;             // 2048
    int xcd = bid & 7;
    int i = bid >> 3;                 // 0..255
    bool is_q = (i < 128);
    int xb = xcd * 128 + (is_q ? i : i - 128);

    const float* A = is_q ? x : ctx;

    __shared__ _Float16 Ts[128 * 192];   // 48KB; idx = pix*192 + (off ^ ((pix&7)<<3))

    int t = threadIdx.x;
    int m0 = xb * 128;
    int b  = m0 / NPIX;
    int p0 = m0 % NPIX;
    const float* Ab = A + (size_t)b * 192 * NPIX + p0;

    int lane = t & 63;
    int wid  = t >> 6;
    int wm = wid & 1;         // 2 m-halves of 64 pixels
    int wn = wid >> 1;        // 4 n-quarters of 48 channels
    int lq = lane & 15;
    int lk = lane >> 4;

    // ---- stage A tile: coalesced 256B reads; batched-wide issue via sched_barrier ----
    {
        int cq = t >> 7, pp = t & 127;
        int sw = (pp & 7) << 3;
        {   // batch 1: 32 loads fully in flight
            float ra[32];
            #pragma unroll
            for (int j = 0; j < 32; j++)
                ra[j] = Ab[(size_t)(cq * 48 + j) * NPIX + pp];
            __builtin_amdgcn_sched_barrier(0);
            #pragma unroll
            for (int j4 = 0; j4 < 8; j4++) {
                int c0 = cq * 48 + j4 * 4;
                U4 u;
                u.p2[0] = __builtin_amdgcn_cvt_pkrtz(ra[j4 * 4],     ra[j4 * 4 + 1]);
                u.p2[1] = __builtin_amdgcn_cvt_pkrtz(ra[j4 * 4 + 2], ra[j4 * 4 + 3]);
                *(f16x4*)&Ts[pp * 192 + (c0 ^ sw)] = u.v4;
            }
        }
        {   // batch 2: remaining 16
            float ra[16];
            #pragma unroll
            for (int j = 0; j < 16; j++)
                ra[j] = Ab[(size_t)(cq * 48 + 32 + j) * NPIX + pp];
            __builtin_amdgcn_sched_barrier(0);
            #pragma unroll
            for (int j4 = 0; j4 < 4; j4++) {
                int c0 = cq * 48 + 32 + j4 * 4;
                U4 u;
                u.p2[0] = __builtin_amdgcn_cvt_pkrtz(ra[j4 * 4],     ra[j4 * 4 + 1]);
                u.p2[1] = __builtin_amdgcn_cvt_pkrtz(ra[j4 * 4 + 2], ra[j4 * 4 + 3]);
                *(f16x4*)&Ts[pp * 192 + (c0 ^ sw)] = u.v4;
            }
        }
    }
    __syncthreads();

    if (is_q) {
        // ---- q: MFMA + LDS output transpose + coalesced stores (proven R11 path) ----
        const _Float16* WT = wt;
        f4 acc[12] = {};
        #pragma unroll
        for (int ks = 0; ks < 6; ks++) {
            f16x8 wf[3];
            #pragma unroll
            for (int ni = 0; ni < 3; ni++)
                wf[ni] = *(const f16x8*)&WT[(size_t)(wn * 48 + ni * 16 + lq) * 192 + ks * 32 + lk * 8];
            #pragma unroll
            for (int mi = 0; mi < 4; mi++) {
                int pix = wm * 64 + mi * 16 + lq;
                f16x8 pfr = *(const f16x8*)&Ts[pix * 192 + ((ks * 32 + lk * 8) ^ ((pix & 7) << 3))];
                #pragma unroll
                for (int ni = 0; ni < 3; ni++)
                    acc[mi * 3 + ni] = __builtin_amdgcn_mfma_f32_16x16x32_f16(wf[ni], pfr, acc[mi * 3 + ni], 0, 0, 0);
            }
        }
        __syncthreads();

        #pragma unroll
        for (int mi = 0; mi < 4; mi++) {
            int pix = wm * 64 + mi * 16 + lq;
            int sw = (pix & 7) << 3;
            #pragma unroll
            for (int ni = 0; ni < 3; ni++) {
                int n0 = wn * 48 + ni * 16 + lk * 4;
                f4 v = acc[mi * 3 + ni];
                f4 bb = *(const f4*)&bq[n0];
                U4 u;
                u.p2[0] = __builtin_amdgcn_cvt_pkrtz((v[0] + bb[0]) * SCALE, (v[1] + bb[1]) * SCALE);
                u.p2[1] = __builtin_amdgcn_cvt_pkrtz((v[2] + bb[2]) * SCALE, (v[3] + bb[3]) * SCALE);
                *(f16x4*)&Ts[pix * 192 + (n0 ^ sw)] = u.v4;
            }
        }
        __syncthreads();

        int p2 = t >> 2, qc = t & 3;
        int sw = (p2 & 7) << 3;
        #pragma unroll
        for (int g = 0; g < 6; g++) {
            f16x8 val = *(const f16x8*)&Ts[p2 * 192 + ((g * 32 + qc * 8) ^ sw)];
            *(f16x8*)(qh + ((size_t)(b * NHEADS + g) * NPIX + p0 + p2) * HD + qc * 8) = val;
        }
    } else {
        // ---- kv: sequential k-loop then v-loop over the SAME staged tile ----
        #pragma unroll
        for (int out = 0; out < 2; out++) {
            const _Float16* WT = wt + (size_t)(1 + out) * 36864;
            const float* bias = out == 0 ? bk : bv;
            _Float16* outp = out == 0 ? kh : vh;
            f4 acc[12] = {};
            #pragma unroll
            for (int ks = 0; ks < 6; ks++) {
                f16x8 wf[3];
                #pragma unroll
                for (int ni = 0; ni < 3; ni++)
                    wf[ni] = *(const f16x8*)&WT[(size_t)(wn * 48 + ni * 16 + lq) * 192 + ks * 32 + lk * 8];
                #pragma unroll
                for (int mi = 0; mi < 4; mi++) {
                    int pix = wm * 64 + mi * 16 + lq;
                    f16x8 pfr = *(const f16x8*)&Ts[pix * 192 + ((ks * 32 + lk * 8) ^ ((pix & 7) << 3))];
                    #pragma unroll
                    for (int ni = 0; ni < 3; ni++)
                        acc[mi * 3 + ni] = __builtin_amdgcn_mfma_f32_16x16x32_f16(wf[ni], pfr, acc[mi * 3 + ni], 0, 0, 0);
                }
            }
            // direct 8B scattered stores (lane owns pixel, 4 consecutive channels)
            #pragma unroll
            for (int mi = 0; mi < 4; mi++) {
                int p = p0 + wm * 64 + mi * 16 + lq;
                #pragma unroll
                for (int ni = 0; ni < 3; ni++) {
                    int n0 = wn * 48 + ni * 16 + lk * 4;
                    int g = n0 >> 5, d0 = n0 & 31;
                    f4 v = acc[mi * 3 + ni];
                    f4 bb = *(const f4*)&bias[n0];
                    U4 u;
                    u.p2[0] = __builtin_amdgcn_cvt_pkrtz(v[0] + bb[0], v[1] + bb[1]);
                    u.p2[1] = __builtin_amdgcn_cvt_pkrtz(v[2] + bb[2], v[3] + bb[3]);
                    *(f16x4*)(outp + ((size_t)(b * NHEADS + g) * NPIX + p) * HD + d0) = u.v4;
                }
            }
        }
    }
}

// ---------------- MFMA neighborhood attention v2 (unchanged from R12/R13) ----------------
#define NA2D_SMEM 68352          // 66560 (Vt) + 1764 (rpb) rounded

template<int K>
__device__ __forceinline__ void na2d_tile(
    const _Float16* __restrict__ qh, const _Float16* __restrict__ kh,
    const _Float16* __restrict__ vh, const float* __restrict__ rpb,
    _Float16* __restrict__ ah, char* smem, int b, int g_head, int hi, int ty, int tx)
{
    constexpr int NS = K / 2;
    constexpr int RW = 2 * K - 1;
    _Float16* Vt = (_Float16*)smem;
    float* rpbs = (float*)(smem + 66560);

    int t = threadIdx.x;
    size_t plane = (size_t)(b * NHEADS + g_head) * NPIX;
    int h0 = ty * 16, w0 = tx * 16;
    int rmin = min(max(h0 - NS, 0), HH - K);
    int rtop = min(max(h0 + 15 - NS, 0), HH - K);
    int rows_n = rtop + K - rmin;
    int cwin0 = min(max(w0 - NS, 0), WW - K);
    int ctop = min(max(w0 + 15 - NS, 0), WW - K);
    int cols_n = ctop + K - cwin0;

    for (int i = t; i < RW * RW; i += 512) rpbs[i] = rpb[(size_t)hi * RW * RW + i];

    int ntask = rows_n * 128;
    for (int idx = t; idx < ntask; idx += 512) {
        int row = idx >> 7;
        int key = (idx >> 2) & 31;
        int dc  = idx & 3;
        f16x8 vvv = {0,0,0,0,0,0,0,0};
        if (key < cols_n) {
            size_t pix = plane + (size_t)(rmin + row) * WW + (cwin0 + key);
            vvv = *(const f16x8*)&vh[pix * HD + dc * 8];
        }
        int m = 8 * ((key & 15) >> 2) + 4 * (key >> 4) + (key & 3);
        #pragma unroll
        for (int j = 0; j < 8; j++)
            Vt[row * 1280 + (dc * 8 + j) * LDK + m] = vvv[j];
    }
    __syncthreads();

    int lane = t & 63, wid = t >> 6;
    int lq = lane & 15, lg = lane >> 4;
    int wq = w0 + lq;
    int c0q = min(max(wq - NS, 0), WW - K);
    int klo = c0q - cwin0;
    int shiftc = cwin0 - wq + K - 1;
    f4 zf4 = {0.f, 0.f, 0.f, 0.f};

    #pragma unroll 1
    for (int qi = 0; qi < 2; qi++) {
        int qr = wid * 2 + qi;
        int h = h0 + qr;
        int r0q = min(max(h - NS, 0), HH - K);
        int row_base = r0q - rmin;
        f16x8 qf = *(const f16x8*)&qh[(plane + (size_t)h * WW + w0 + lq) * HD + lg * 8];
        f4 acc0 = zf4, acc1 = zf4;
        float lsum = 0.f;

        #pragma unroll 1
        for (int ki = 0; ki < K; ki++) {
            int row = row_base + ki;
            const _Float16* kgrow = kh + (plane + (size_t)(rmin + row) * WW + cwin0) * HD;
            f16x8 a0 = *(const f16x8*)&kgrow[(size_t)lq * HD + lg * 8];
            f16x8 a1 = *(const f16x8*)&kgrow[(size_t)(16 + lq) * HD + lg * 8];
            f4 s0 = __builtin_amdgcn_mfma_f32_16x16x32_f16(a0, qf, zf4, 0, 0, 0);
            f4 s1 = __builtin_amdgcn_mfma_f32_16x16x32_f16(a1, qf, zf4, 0, 0, 0);

            int rel_r = r0q + ki - h + K - 1;
            const float* rrow = rpbs + rel_r * RW;
            float pf[2][4];
            #pragma unroll
            for (int c = 0; c < 2; c++) {
                #pragma unroll
                for (int r = 0; r < 4; r++) {
                    int key_local = c * 16 + 4 * lg + r;
                    int rc = key_local + shiftc;
                    rc = min(max(rc, 0), RW - 1);
                    float biasv = rrow[rc];
                    bool valid = (unsigned)(key_local - klo) < (unsigned)K;
                    float sv = (c ? s1[r] : s0[r]) + biasv;
                    float pv = valid ? __expf(sv) : 0.f;
                    pf[c][r] = pv;
                    lsum += pv;
                }
            }
            union { g2 p[4]; f16x8 v; } P;
            P.p[0] = __builtin_amdgcn_cvt_pkrtz(pf[0][0], pf[0][1]);
            P.p[1] = __builtin_amdgcn_cvt_pkrtz(pf[0][2], pf[0][3]);
            P.p[2] = __builtin_amdgcn_cvt_pkrtz(pf[1][0], pf[1][1]);
            P.p[3] = __builtin_amdgcn_cvt_pkrtz(pf[1][2], pf[1][3]);

            const _Float16* vbase = &Vt[row * 1280 + lg * 8];
            f16x8 b0 = *(const f16x8*)&vbase[lq * LDK];
            f16x8 b1 = *(const f16x8*)&vbase[(16 + lq) * LDK];
            acc0 = __builtin_amdgcn_mfma_f32_16x16x32_f16(P.v, b0, acc0, 0, 0, 0);
            acc1 = __builtin_amdgcn_mfma_f32_16x16x32_f16(P.v, b1, acc1, 0, 0, 0);
        }

        lsum += __shfl_xor(lsum, 16);
        lsum += __shfl_xor(lsum, 32);
        float inv = 1.f / lsum;
        _Float16* obase = ah + (plane + (size_t)h * WW + w0) * HD;
        #pragma unroll
        for (int r = 0; r < 4; r++) {
            float ir = __shfl(inv, 4 * lg + r);
            obase[(4 * lg + r) * HD + lq]      = (_Float16)(acc0[r] * ir);
            obase[(4 * lg + r) * HD + lq + 16] = (_Float16)(acc1[r] * ir);
        }
    }
}

__global__ __launch_bounds__(512) void na2d_mfma(
    const _Float16* __restrict__ qh, const _Float16* __restrict__ kh,
    const _Float16* __restrict__ vh,
    const float* __restrict__ rpb0, const float* __restrict__ rpb1,
    const float* __restrict__ rpb2, _Float16* __restrict__ ah)
{
    extern __shared__ char smem[];
    int bid = blockIdx.x;
    int xcd = bid & 7;
    int i = bid >> 3;
    int phase = i >> 7;
    int j = i & 127;
    int lb = xcd * 128 + j;
    int bz = lb >> 6;
    int tile = lb & 63;
    int b = bz >> 1, hi = bz & 1;
    int ty = tile >> 3, tx = tile & 7;
    if (phase == 0)      na2d_tile<7>(qh, kh, vh, rpb0, ah, smem, b, 0 + hi, hi, ty, tx);
    else if (phase == 1) na2d_tile<9>(qh, kh, vh, rpb1, ah, smem, b, 2 + hi, hi, ty, tx);
    else                 na2d_tile<11>(qh, kh, vh, rpb2, ah, smem, b, 4 + hi, hi, ty, tx);
}

// ---------------- MFMA output projection (unchanged from R9-R13) ----------------
__global__ __launch_bounds__(512) void oproj_mfma(
    const _Float16* __restrict__ ah, const _Float16* __restrict__ woT,
    const float* __restrict__ bo, float* __restrict__ outp)
{
    int t = threadIdx.x;
    int m0 = blockIdx.x * 128;
    int b  = m0 / NPIX;
    int p0 = m0 % NPIX;

    int lane = t & 63;
    int wid  = t >> 6;
    int wm = wid & 1;
    int wn = wid >> 1;
    int lr = lane & 15;
    int lk = lane >> 4;

    f4 acc[4][3] = {};

    #pragma unroll
    for (int ks = 0; ks < 6; ks++) {
        const _Float16* abase = ah + (size_t)(b * NHEADS + ks) * NPIX * HD;
        f16x8 af[4], bf[3];
        #pragma unroll
        for (int mi = 0; mi < 4; mi++)
            af[mi] = *(const f16x8*)&abase[(size_t)(p0 + wm * 64 + mi * 16 + lr) * HD + lk * 8];
        #pragma unroll
        for (int ni = 0; ni < 3; ni++)
            bf[ni] = *(const f16x8*)&woT[(size_t)(wn * 48 + ni * 16 + lr) * 192 + ks * 32 + lk * 8];
        #pragma unroll
        for (int mi = 0; mi < 4; mi++)
            #pragma unroll
            for (int ni = 0; ni < 3; ni++)
                acc[mi][ni] = __builtin_amdgcn_mfma_f32_16x16x32_f16(af[mi], bf[ni], acc[mi][ni], 0, 0, 0);
    }

    #pragma unroll
    for (int ni = 0; ni < 3; ni++) {
        int n = wn * 48 + ni * 16 + lr;
        float bb = bo[n];
        float* obase = outp + ((size_t)b * 192 + n) * NPIX + p0 + wm * 64;
        #pragma unroll
        for (int mi = 0; mi < 4; mi++) {
            f4 v = acc[mi][ni];
            v[0] += bb; v[1] += bb; v[2] += bb; v[3] += bb;
            *(f4*)&obase[mi * 16 + lk * 4] = v;
        }
    }
}

extern "C" void kernel_launch(void* const* d_in, const int* in_sizes, int n_in,
                              void* d_out, int out_size, void* d_ws, size_t ws_size,
                              hipStream_t stream) {
    const float* x    = (const float*)d_in[0];
    const float* ctx  = (const float*)d_in[1];
    const float* Wq   = (const float*)d_in[2];
    const float* bq   = (const float*)d_in[3];
    const float* Wk   = (const float*)d_in[4];
    const float* bk   = (const float*)d_in[5];
    const float* Wv   = (const float*)d_in[6];
    const float* bv   = (const float*)d_in[7];
    const float* Wo   = (const float*)d_in[8];
    const float* bo   = (const float*)d_in[9];
    const float* rpb0 = (const float*)d_in[10];
    const float* rpb1 = (const float*)d_in[11];
    const float* rpb2 = (const float*)d_in[12];

    size_t N = (size_t)NB * NHEADS * NPIX * HD;   // 25,165,824 fp16 elements = 50.33MB
    _Float16* qh = (_Float16*)d_ws;
    _Float16* kh = qh + N;
    _Float16* vh = kh + N;
    _Float16* ah = vh + N;
    float* outp = (float*)d_out;

    // parking: WT fp16 in second half of d_out (dead until oproj); woT in qh (dead after na2d)
    _Float16* wt  = (_Float16*)d_out + N;
    _Float16* woT = qh;

    (void)hipFuncSetAttribute((const void*)na2d_mfma,
                              hipFuncAttributeMaxDynamicSharedMemorySize, NA2D_SMEM);

    prep_wt<<<216, 512, 0, stream>>>(Wq, Wk, Wv, wt);
    proj_mfma<<<2048, 512, 0, stream>>>(x, ctx, wt, bq, bk, bv, qh, kh, vh);
    na2d_mfma<<<3072, 512, NA2D_SMEM, stream>>>(qh, kh, vh, rpb0, rpb1, rpb2, ah);
    prep_wo<<<72, 512, 0, stream>>>(Wo, woT);
    oproj_mfma<<<1024, 512, 0, stream>>>(ah, woT, bo, outp);
}

// Round 15
// 238.761 us; speedup vs baseline: 1.0804x; 1.0634x over previous
//
#include <hip/hip_runtime.h>
#include <hip/hip_fp16.h>

#define HH 128
#define WW 128
#define NPIX (HH*WW)
#define NB 8
#define NHEADS 6
#define HD 32
#define SCALE 0.17677669529663687f

typedef _Float16 h2 __attribute__((ext_vector_type(2)));
typedef __fp16 g2 __attribute__((ext_vector_type(2)));
typedef _Float16 f16x4 __attribute__((ext_vector_type(4)));
typedef _Float16 f16x8 __attribute__((ext_vector_type(8)));
typedef float f4 __attribute__((ext_vector_type(4)));
typedef float f2 __attribute__((ext_vector_type(2)));

#define LDK 40    // na2d Vt padded stride
union U4 { g2 p2[2]; f16x4 v4; };

// ---------------- prep: WT[z][n][k] fp16 from W[z][k][n] fp32 ----------------
__global__ __launch_bounds__(512) void prep_wt(
    const float* __restrict__ Wq, const float* __restrict__ Wk,
    const float* __restrict__ Wv, _Float16* __restrict__ wt)
{
    int idx = blockIdx.x * 512 + threadIdx.x;      // 3*36864 total
    int mat = idx / 36864, rem = idx % 36864;
    int k = rem / 192, n = rem % 192;              // coalesced read over n
    const float* W = mat == 0 ? Wq : (mat == 1 ? Wk : Wv);
    wt[(size_t)mat * 36864 + (size_t)n * 192 + k] = (_Float16)W[(size_t)k * 192 + n];
}

__global__ __launch_bounds__(512) void prep_wo(
    const float* __restrict__ Wo, _Float16* __restrict__ woT)
{
    int idx = blockIdx.x * 512 + threadIdx.x;      // 36864
    int k = idx / 192, n = idx % 192;
    woT[(size_t)n * 192 + k] = (_Float16)Wo[(size_t)k * 192 + n];
}

// ---------------- MFMA projection v10: float2 NT staging + setprio, k/v fused ----------------
// 2048 blocks x 512 threads: per XCD 128 q-tiles then 128 kv-tiles (ctx staged ONCE).
// Staging: 24 float2 nontemporal loads per thread (512B/wave/instr, x/ctx are read-once
// streams -> NT avoids evicting WT + write-combining lines from L2).
__global__ __launch_bounds__(512, 4) void proj_mfma(
    const float* __restrict__ x, const float* __restrict__ ctx,
    const _Float16* __restrict__ wt,
    const float* __restrict__ bq, const float* __restrict__ bk, const float* __restrict__ bv,
    _Float16* __restrict__ qh, _Float16* __restrict__ kh, _Float16* __restrict__ vh)
{
    int bid = blockIdx.x;             // 2048
    int xcd = bid & 7;
    int i = bid >> 3;                 // 0..255
    bool is_q = (i < 128);
    int xb = xcd * 128 + (is_q ? i : i - 128);

    const float* A = is_q ? x : ctx;

    __shared__ _Float16 Ts[128 * 192];   // 48KB; idx = pix*192 + (off ^ ((pix&7)<<3))

    int t = threadIdx.x;
    int m0 = xb * 128;
    int b  = m0 / NPIX;
    int p0 = m0 % NPIX;
    const float* Ab = A + (size_t)b * 192 * NPIX + p0;

    int lane = t & 63;
    int wid  = t >> 6;
    int wm = wid & 1;         // 2 m-halves of 64 pixels
    int wn = wid >> 1;        // 4 n-quarters of 48 channels
    int lq = lane & 15;
    int lk = lane >> 4;

    // ---- stage A tile: 24 x float2 NT loads/thread (pixel pair), swizzled b64 LDS writes ----
    {
        int pq = t & 63;               // pixel pair: 2pq, 2pq+1
        int cg = t >> 6;               // 8 channel groups x 24 channels
        int c_base = cg * 24;
        f2 ra[24];
        #pragma unroll
        for (int j = 0; j < 24; j++)
            ra[j] = __builtin_nontemporal_load((const f2*)&Ab[(size_t)(c_base + j) * NPIX + 2 * pq]);
        __builtin_amdgcn_sched_barrier(0);
        #pragma unroll
        for (int r = 0; r < 2; r++) {
            int pix = 2 * pq + r;
            int sw = (pix & 7) << 3;
            #pragma unroll
            for (int j4 = 0; j4 < 6; j4++) {
                int c0 = c_base + j4 * 4;
                U4 u;
                u.p2[0] = __builtin_amdgcn_cvt_pkrtz(ra[j4 * 4][r],     ra[j4 * 4 + 1][r]);
                u.p2[1] = __builtin_amdgcn_cvt_pkrtz(ra[j4 * 4 + 2][r], ra[j4 * 4 + 3][r]);
                *(f16x4*)&Ts[pix * 192 + (c0 ^ sw)] = u.v4;
            }
        }
    }
    __syncthreads();

    if (is_q) {
        const _Float16* WT = wt;
        f4 acc[12] = {};
        #pragma unroll
        for (int ks = 0; ks < 6; ks++) {
            f16x8 wf[3];
            #pragma unroll
            for (int ni = 0; ni < 3; ni++)
                wf[ni] = *(const f16x8*)&WT[(size_t)(wn * 48 + ni * 16 + lq) * 192 + ks * 32 + lk * 8];
            #pragma unroll
            for (int mi = 0; mi < 4; mi++) {
                int pix = wm * 64 + mi * 16 + lq;
                f16x8 pfr = *(const f16x8*)&Ts[pix * 192 + ((ks * 32 + lk * 8) ^ ((pix & 7) << 3))];
                __builtin_amdgcn_s_setprio(1);
                #pragma unroll
                for (int ni = 0; ni < 3; ni++)
                    acc[mi * 3 + ni] = __builtin_amdgcn_mfma_f32_16x16x32_f16(wf[ni], pfr, acc[mi * 3 + ni], 0, 0, 0);
                __builtin_amdgcn_s_setprio(0);
            }
        }
        __syncthreads();

        #pragma unroll
        for (int mi = 0; mi < 4; mi++) {
            int pix = wm * 64 + mi * 16 + lq;
            int sw = (pix & 7) << 3;
            #pragma unroll
            for (int ni = 0; ni < 3; ni++) {
                int n0 = wn * 48 + ni * 16 + lk * 4;
                f4 v = acc[mi * 3 + ni];
                f4 bb = *(const f4*)&bq[n0];
                U4 u;
                u.p2[0] = __builtin_amdgcn_cvt_pkrtz((v[0] + bb[0]) * SCALE, (v[1] + bb[1]) * SCALE);
                u.p2[1] = __builtin_amdgcn_cvt_pkrtz((v[2] + bb[2]) * SCALE, (v[3] + bb[3]) * SCALE);
                *(f16x4*)&Ts[pix * 192 + (n0 ^ sw)] = u.v4;
            }
        }
        __syncthreads();

        int p2 = t >> 2, qc = t & 3;
        int sw = (p2 & 7) << 3;
        #pragma unroll
        for (int g = 0; g < 6; g++) {
            f16x8 val = *(const f16x8*)&Ts[p2 * 192 + ((g * 32 + qc * 8) ^ sw)];
            *(f16x8*)(qh + ((size_t)(b * NHEADS + g) * NPIX + p0 + p2) * HD + qc * 8) = val;
        }
    } else {
        #pragma unroll
        for (int out = 0; out < 2; out++) {
            const _Float16* WT = wt + (size_t)(1 + out) * 36864;
            const float* bias = out == 0 ? bk : bv;
            _Float16* outp = out == 0 ? kh : vh;
            f4 acc[12] = {};
            #pragma unroll
            for (int ks = 0; ks < 6; ks++) {
                f16x8 wf[3];
                #pragma unroll
                for (int ni = 0; ni < 3; ni++)
                    wf[ni] = *(const f16x8*)&WT[(size_t)(wn * 48 + ni * 16 + lq) * 192 + ks * 32 + lk * 8];
                #pragma unroll
                for (int mi = 0; mi < 4; mi++) {
                    int pix = wm * 64 + mi * 16 + lq;
                    f16x8 pfr = *(const f16x8*)&Ts[pix * 192 + ((ks * 32 + lk * 8) ^ ((pix & 7) << 3))];
                    __builtin_amdgcn_s_setprio(1);
                    #pragma unroll
                    for (int ni = 0; ni < 3; ni++)
                        acc[mi * 3 + ni] = __builtin_amdgcn_mfma_f32_16x16x32_f16(wf[ni], pfr, acc[mi * 3 + ni], 0, 0, 0);
                    __builtin_amdgcn_s_setprio(0);
                }
            }
            #pragma unroll
            for (int mi = 0; mi < 4; mi++) {
                int p = p0 + wm * 64 + mi * 16 + lq;
                #pragma unroll
                for (int ni = 0; ni < 3; ni++) {
                    int n0 = wn * 48 + ni * 16 + lk * 4;
                    int g = n0 >> 5, d0 = n0 & 31;
                    f4 v = acc[mi * 3 + ni];
                    f4 bb = *(const f4*)&bias[n0];
                    U4 u;
                    u.p2[0] = __builtin_amdgcn_cvt_pkrtz(v[0] + bb[0], v[1] + bb[1]);
                    u.p2[1] = __builtin_amdgcn_cvt_pkrtz(v[2] + bb[2], v[3] + bb[3]);
                    *(f16x4*)(outp + ((size_t)(b * NHEADS + g) * NPIX + p) * HD + d0) = u.v4;
                }
            }
        }
    }
}

// ---------------- MFMA neighborhood attention v3: R12 + setprio ----------------
#define NA2D_SMEM 68352          // 66560 (Vt) + 1764 (rpb) rounded

template<int K>
__device__ __forceinline__ void na2d_tile(
    const _Float16* __restrict__ qh, const _Float16* __restrict__ kh,
    const _Float16* __restrict__ vh, const float* __restrict__ rpb,
    _Float16* __restrict__ ah, char* smem, int b, int g_head, int hi, int ty, int tx)
{
    constexpr int NS = K / 2;
    constexpr int RW = 2 * K - 1;
    _Float16* Vt = (_Float16*)smem;
    float* rpbs = (float*)(smem + 66560);

    int t = threadIdx.x;
    size_t plane = (size_t)(b * NHEADS + g_head) * NPIX;
    int h0 = ty * 16, w0 = tx * 16;
    int rmin = min(max(h0 - NS, 0), HH - K);
    int rtop = min(max(h0 + 15 - NS, 0), HH - K);
    int rows_n = rtop + K - rmin;
    int cwin0 = min(max(w0 - NS, 0), WW - K);
    int ctop = min(max(w0 + 15 - NS, 0), WW - K);
    int cols_n = ctop + K - cwin0;

    for (int i = t; i < RW * RW; i += 512) rpbs[i] = rpb[(size_t)hi * RW * RW + i];

    int ntask = rows_n * 128;
    for (int idx = t; idx < ntask; idx += 512) {
        int row = idx >> 7;
        int key = (idx >> 2) & 31;
        int dc  = idx & 3;
        f16x8 vvv = {0,0,0,0,0,0,0,0};
        if (key < cols_n) {
            size_t pix = plane + (size_t)(rmin + row) * WW + (cwin0 + key);
            vvv = *(const f16x8*)&vh[pix * HD + dc * 8];
        }
        int m = 8 * ((key & 15) >> 2) + 4 * (key >> 4) + (key & 3);
        #pragma unroll
        for (int j = 0; j < 8; j++)
            Vt[row * 1280 + (dc * 8 + j) * LDK + m] = vvv[j];
    }
    __syncthreads();

    int lane = t & 63, wid = t >> 6;
    int lq = lane & 15, lg = lane >> 4;
    int wq = w0 + lq;
    int c0q = min(max(wq - NS, 0), WW - K);
    int klo = c0q - cwin0;
    int shiftc = cwin0 - wq + K - 1;
    f4 zf4 = {0.f, 0.f, 0.f, 0.f};

    #pragma unroll 1
    for (int qi = 0; qi < 2; qi++) {
        int qr = wid * 2 + qi;
        int h = h0 + qr;
        int r0q = min(max(h - NS, 0), HH - K);
        int row_base = r0q - rmin;
        f16x8 qf = *(const f16x8*)&qh[(plane + (size_t)h * WW + w0 + lq) * HD + lg * 8];
        f4 acc0 = zf4, acc1 = zf4;
        float lsum = 0.f;

        #pragma unroll 1
        for (int ki = 0; ki < K; ki++) {
            int row = row_base + ki;
            const _Float16* kgrow = kh + (plane + (size_t)(rmin + row) * WW + cwin0) * HD;
            f16x8 a0 = *(const f16x8*)&kgrow[(size_t)lq * HD + lg * 8];
            f16x8 a1 = *(const f16x8*)&kgrow[(size_t)(16 + lq) * HD + lg * 8];
            __builtin_amdgcn_s_setprio(1);
            f4 s0 = __builtin_amdgcn_mfma_f32_16x16x32_f16(a0, qf, zf4, 0, 0, 0);
            f4 s1 = __builtin_amdgcn_mfma_f32_16x16x32_f16(a1, qf, zf4, 0, 0, 0);
            __builtin_amdgcn_s_setprio(0);

            int rel_r = r0q + ki - h + K - 1;
            const float* rrow = rpbs + rel_r * RW;
            float pf[2][4];
            #pragma unroll
            for (int c = 0; c < 2; c++) {
                #pragma unroll
                for (int r = 0; r < 4; r++) {
                    int key_local = c * 16 + 4 * lg + r;
                    int rc = key_local + shiftc;
                    rc = min(max(rc, 0), RW - 1);
                    float biasv = rrow[rc];
                    bool valid = (unsigned)(key_local - klo) < (unsigned)K;
                    float sv = (c ? s1[r] : s0[r]) + biasv;
                    float pv = valid ? __expf(sv) : 0.f;
                    pf[c][r] = pv;
                    lsum += pv;
                }
            }
            union { g2 p[4]; f16x8 v; } P;
            P.p[0] = __builtin_amdgcn_cvt_pkrtz(pf[0][0], pf[0][1]);
            P.p[1] = __builtin_amdgcn_cvt_pkrtz(pf[0][2], pf[0][3]);
            P.p[2] = __builtin_amdgcn_cvt_pkrtz(pf[1][0], pf[1][1]);
            P.p[3] = __builtin_amdgcn_cvt_pkrtz(pf[1][2], pf[1][3]);

            const _Float16* vbase = &Vt[row * 1280 + lg * 8];
            f16x8 b0 = *(const f16x8*)&vbase[lq * LDK];
            f16x8 b1 = *(const f16x8*)&vbase[(16 + lq) * LDK];
            __builtin_amdgcn_s_setprio(1);
            acc0 = __builtin_amdgcn_mfma_f32_16x16x32_f16(P.v, b0, acc0, 0, 0, 0);
            acc1 = __builtin_amdgcn_mfma_f32_16x16x32_f16(P.v, b1, acc1, 0, 0, 0);
            __builtin_amdgcn_s_setprio(0);
        }

        lsum += __shfl_xor(lsum, 16);
        lsum += __shfl_xor(lsum, 32);
        float inv = 1.f / lsum;
        _Float16* obase = ah + (plane + (size_t)h * WW + w0) * HD;
        #pragma unroll
        for (int r = 0; r < 4; r++) {
            float ir = __shfl(inv, 4 * lg + r);
            obase[(4 * lg + r) * HD + lq]      = (_Float16)(acc0[r] * ir);
            obase[(4 * lg + r) * HD + lq + 16] = (_Float16)(acc1[r] * ir);
        }
    }
}

__global__ __launch_bounds__(512) void na2d_mfma(
    const _Float16* __restrict__ qh, const _Float16* __restrict__ kh,
    const _Float16* __restrict__ vh,
    const float* __restrict__ rpb0, const float* __restrict__ rpb1,
    const float* __restrict__ rpb2, _Float16* __restrict__ ah)
{
    extern __shared__ char smem[];
    int bid = blockIdx.x;
    int xcd = bid & 7;
    int i = bid >> 3;
    int phase = i >> 7;
    int j = i & 127;
    int lb = xcd * 128 + j;
    int bz = lb >> 6;
    int tile = lb & 63;
    int b = bz >> 1, hi = bz & 1;
    int ty = tile >> 3, tx = tile & 7;
    if (phase == 0)      na2d_tile<7>(qh, kh, vh, rpb0, ah, smem, b, 0 + hi, hi, ty, tx);
    else if (phase == 1) na2d_tile<9>(qh, kh, vh, rpb1, ah, smem, b, 2 + hi, hi, ty, tx);
    else                 na2d_tile<11>(qh, kh, vh, rpb2, ah, smem, b, 4 + hi, hi, ty, tx);
}

// ---------------- MFMA output projection (unchanged from R9-R14) ----------------
__global__ __launch_bounds__(512) void oproj_mfma(
    const _Float16* __restrict__ ah, const _Float16* __restrict__ woT,
    const float* __restrict__ bo, float* __restrict__ outp)
{
    int t = threadIdx.x;
    int m0 = blockIdx.x * 128;
    int b  = m0 / NPIX;
    int p0 = m0 % NPIX;

    int lane = t & 63;
    int wid  = t >> 6;
    int wm = wid & 1;
    int wn = wid >> 1;
    int lr = lane & 15;
    int lk = lane >> 4;

    f4 acc[4][3] = {};

    #pragma unroll
    for (int ks = 0; ks < 6; ks++) {
        const _Float16* abase = ah + (size_t)(b * NHEADS + ks) * NPIX * HD;
        f16x8 af[4], bf[3];
        #pragma unroll
        for (int mi = 0; mi < 4; mi++)
            af[mi] = *(const f16x8*)&abase[(size_t)(p0 + wm * 64 + mi * 16 + lr) * HD + lk * 8];
        #pragma unroll
        for (int ni = 0; ni < 3; ni++)
            bf[ni] = *(const f16x8*)&woT[(size_t)(wn * 48 + ni * 16 + lr) * 192 + ks * 32 + lk * 8];
        #pragma unroll
        for (int mi = 0; mi < 4; mi++)
            #pragma unroll
            for (int ni = 0; ni < 3; ni++)
                acc[mi][ni] = __builtin_amdgcn_mfma_f32_16x16x32_f16(af[mi], bf[ni], acc[mi][ni], 0, 0, 0);
    }

    #pragma unroll
    for (int ni = 0; ni < 3; ni++) {
        int n = wn * 48 + ni * 16 + lr;
        float bb = bo[n];
        float* obase = outp + ((size_t)b * 192 + n) * NPIX + p0 + wm * 64;
        #pragma unroll
        for (int mi = 0; mi < 4; mi++) {
            f4 v = acc[mi][ni];
            v[0] += bb; v[1] += bb; v[2] += bb; v[3] += bb;
            *(f4*)&obase[mi * 16 + lk * 4] = v;
        }
    }
}

extern "C" void kernel_launch(void* const* d_in, const int* in_sizes, int n_in,
                              void* d_out, int out_size, void* d_ws, size_t ws_size,
                              hipStream_t stream) {
    const float* x    = (const float*)d_in[0];
    const float* ctx  = (const float*)d_in[1];
    const float* Wq   = (const float*)d_in[2];
    const float* bq   = (const float*)d_in[3];
    const float* Wk   = (const float*)d_in[4];
    const float* bk   = (const float*)d_in[5];
    const float* Wv   = (const float*)d_in[6];
    const float* bv   = (const float*)d_in[7];
    const float* Wo   = (const float*)d_in[8];
    const float* bo   = (const float*)d_in[9];
    const float* rpb0 = (const float*)d_in[10];
    const float* rpb1 = (const float*)d_in[11];
    const float* rpb2 = (const float*)d_in[12];

    size_t N = (size_t)NB * NHEADS * NPIX * HD;   // 25,165,824 fp16 elements = 50.33MB
    _Float16* qh = (_Float16*)d_ws;
    _Float16* kh = qh + N;
    _Float16* vh = kh + N;
    _Float16* ah = vh + N;
    float* outp = (float*)d_out;

    // parking: WT fp16 in second half of d_out (dead until oproj); woT in qh (dead after na2d)
    _Float16* wt  = (_Float16*)d_out + N;
    _Float16* woT = qh;

    (void)hipFuncSetAttribute((const void*)na2d_mfma,
                              hipFuncAttributeMaxDynamicSharedMemorySize, NA2D_SMEM);

    prep_wt<<<216, 512, 0, stream>>>(Wq, Wk, Wv, wt);
    proj_mfma<<<2048, 512, 0, stream>>>(x, ctx, wt, bq, bk, bv, qh, kh, vh);
    na2d_mfma<<<3072, 512, NA2D_SMEM, stream>>>(qh, kh, vh, rpb0, rpb1, rpb2, ah);
    prep_wo<<<72, 512, 0, stream>>>(Wo, woT);
    oproj_mfma<<<1024, 512, 0, stream>>>(ah, woT, bo, outp);
}

// Round 16
// 237.135 us; speedup vs baseline: 1.0878x; 1.0069x over previous
//
#include <hip/hip_runtime.h>
#include <hip/hip_fp16.h>

#define HH 128
#define WW 128
#define NPIX (HH*WW)
#define NB 8
#define NHEADS 6
#define HD 32
#define SCALE 0.17677669529663687f

typedef _Float16 h2 __attribute__((ext_vector_type(2)));
typedef __fp16 g2 __attribute__((ext_vector_type(2)));
typedef _Float16 f16x4 __attribute__((ext_vector_type(4)));
typedef _Float16 f16x8 __attribute__((ext_vector_type(8)));
typedef float f4 __attribute__((ext_vector_type(4)));
typedef float f2 __attribute__((ext_vector_type(2)));

#define LDK 40    // na2d Vt padded stride
union U4 { g2 p2[2]; f16x4 v4; };

// ---------------- prep: WT[z][n][k] fp16 from W[z][k][n] fp32 ----------------
__global__ __launch_bounds__(512) void prep_wt(
    const float* __restrict__ Wq, const float* __restrict__ Wk,
    const float* __restrict__ Wv, _Float16* __restrict__ wt)
{
    int idx = blockIdx.x * 512 + threadIdx.x;      // 3*36864 total
    int mat = idx / 36864, rem = idx % 36864;
    int k = rem / 192, n = rem % 192;              // coalesced read over n
    const float* W = mat == 0 ? Wq : (mat == 1 ? Wk : Wv);
    wt[(size_t)mat * 36864 + (size_t)n * 192 + k] = (_Float16)W[(size_t)k * 192 + n];
}

__global__ __launch_bounds__(512) void prep_wo(
    const float* __restrict__ Wo, _Float16* __restrict__ woT)
{
    int idx = blockIdx.x * 512 + threadIdx.x;      // 36864
    int k = idx / 192, n = idx % 192;
    woT[(size_t)n * 192 + k] = (_Float16)Wo[(size_t)k * 192 + n];
}

// ---------------- MFMA projection v11: float4 NT staging + setprio, k/v fused ----------------
// 2048 blocks x 512 threads: per XCD 128 q-tiles then 128 kv-tiles (ctx staged ONCE).
// Staging: 12 float4 nontemporal loads per thread (1KB/wave across 2 segments per instr).
__global__ __launch_bounds__(512, 4) void proj_mfma(
    const float* __restrict__ x, const float* __restrict__ ctx,
    const _Float16* __restrict__ wt,
    const float* __restrict__ bq, const float* __restrict__ bk, const float* __restrict__ bv,
    _Float16* __restrict__ qh, _Float16* __restrict__ kh, _Float16* __restrict__ vh)
{
    int bid = blockIdx.x;             // 2048
    int xcd = bid & 7;
    int i = bid >> 3;                 // 0..255
    bool is_q = (i < 128);
    int xb = xcd * 128 + (is_q ? i : i - 128);

    const float* A = is_q ? x : ctx;

    __shared__ _Float16 Ts[128 * 192];   // 48KB; idx = pix*192 + (off ^ ((pix&7)<<3))

    int t = threadIdx.x;
    int m0 = xb * 128;
    int b  = m0 / NPIX;
    int p0 = m0 % NPIX;
    const float* Ab = A + (size_t)b * 192 * NPIX + p0;

    int lane = t & 63;
    int wid  = t >> 6;
    int wm = wid & 1;         // 2 m-halves of 64 pixels
    int wn = wid >> 1;        // 4 n-quarters of 48 channels
    int lq = lane & 15;
    int lk = lane >> 4;

    // ---- stage A tile: 12 x float4 NT loads/thread (pixel quad), swizzled 8B LDS writes ----
    {
        int pq = t & 31;               // pixel quad: 4pq..4pq+3
        int cg = t >> 5;               // 16 channel groups x 12 channels
        int c_base = cg * 12;
        f4 ra[12];
        #pragma unroll
        for (int j = 0; j < 12; j++)
            ra[j] = __builtin_nontemporal_load((const f4*)&Ab[(size_t)(c_base + j) * NPIX + 4 * pq]);
        __builtin_amdgcn_sched_barrier(0);
        #pragma unroll
        for (int r = 0; r < 4; r++) {
            int pix = 4 * pq + r;
            int sw = (pix & 7) << 3;
            #pragma unroll
            for (int j4 = 0; j4 < 3; j4++) {
                int c0 = c_base + j4 * 4;
                U4 u;
                u.p2[0] = __builtin_amdgcn_cvt_pkrtz(ra[j4 * 4][r],     ra[j4 * 4 + 1][r]);
                u.p2[1] = __builtin_amdgcn_cvt_pkrtz(ra[j4 * 4 + 2][r], ra[j4 * 4 + 3][r]);
                *(f16x4*)&Ts[pix * 192 + (c0 ^ sw)] = u.v4;
            }
        }
    }
    __syncthreads();

    if (is_q) {
        const _Float16* WT = wt;
        f4 acc[12] = {};
        #pragma unroll
        for (int ks = 0; ks < 6; ks++) {
            f16x8 wf[3];
            #pragma unroll
            for (int ni = 0; ni < 3; ni++)
                wf[ni] = *(const f16x8*)&WT[(size_t)(wn * 48 + ni * 16 + lq) * 192 + ks * 32 + lk * 8];
            #pragma unroll
            for (int mi = 0; mi < 4; mi++) {
                int pix = wm * 64 + mi * 16 + lq;
                f16x8 pfr = *(const f16x8*)&Ts[pix * 192 + ((ks * 32 + lk * 8) ^ ((pix & 7) << 3))];
                __builtin_amdgcn_s_setprio(1);
                #pragma unroll
                for (int ni = 0; ni < 3; ni++)
                    acc[mi * 3 + ni] = __builtin_amdgcn_mfma_f32_16x16x32_f16(wf[ni], pfr, acc[mi * 3 + ni], 0, 0, 0);
                __builtin_amdgcn_s_setprio(0);
            }
        }
        __syncthreads();

        #pragma unroll
        for (int mi = 0; mi < 4; mi++) {
            int pix = wm * 64 + mi * 16 + lq;
            int sw = (pix & 7) << 3;
            #pragma unroll
            for (int ni = 0; ni < 3; ni++) {
                int n0 = wn * 48 + ni * 16 + lk * 4;
                f4 v = acc[mi * 3 + ni];
                f4 bb = *(const f4*)&bq[n0];
                U4 u;
                u.p2[0] = __builtin_amdgcn_cvt_pkrtz((v[0] + bb[0]) * SCALE, (v[1] + bb[1]) * SCALE);
                u.p2[1] = __builtin_amdgcn_cvt_pkrtz((v[2] + bb[2]) * SCALE, (v[3] + bb[3]) * SCALE);
                *(f16x4*)&Ts[pix * 192 + (n0 ^ sw)] = u.v4;
            }
        }
        __syncthreads();

        int p2 = t >> 2, qc = t & 3;
        int sw = (p2 & 7) << 3;
        #pragma unroll
        for (int g = 0; g < 6; g++) {
            f16x8 val = *(const f16x8*)&Ts[p2 * 192 + ((g * 32 + qc * 8) ^ sw)];
            *(f16x8*)(qh + ((size_t)(b * NHEADS + g) * NPIX + p0 + p2) * HD + qc * 8) = val;
        }
    } else {
        #pragma unroll
        for (int out = 0; out < 2; out++) {
            const _Float16* WT = wt + (size_t)(1 + out) * 36864;
            const float* bias = out == 0 ? bk : bv;
            _Float16* outp = out == 0 ? kh : vh;
            f4 acc[12] = {};
            #pragma unroll
            for (int ks = 0; ks < 6; ks++) {
                f16x8 wf[3];
                #pragma unroll
                for (int ni = 0; ni < 3; ni++)
                    wf[ni] = *(const f16x8*)&WT[(size_t)(wn * 48 + ni * 16 + lq) * 192 + ks * 32 + lk * 8];
                #pragma unroll
                for (int mi = 0; mi < 4; mi++) {
                    int pix = wm * 64 + mi * 16 + lq;
                    f16x8 pfr = *(const f16x8*)&Ts[pix * 192 + ((ks * 32 + lk * 8) ^ ((pix & 7) << 3))];
                    __builtin_amdgcn_s_setprio(1);
                    #pragma unroll
                    for (int ni = 0; ni < 3; ni++)
                        acc[mi * 3 + ni] = __builtin_amdgcn_mfma_f32_16x16x32_f16(wf[ni], pfr, acc[mi * 3 + ni], 0, 0, 0);
                    __builtin_amdgcn_s_setprio(0);
                }
            }
            #pragma unroll
            for (int mi = 0; mi < 4; mi++) {
                int p = p0 + wm * 64 + mi * 16 + lq;
                #pragma unroll
                for (int ni = 0; ni < 3; ni++) {
                    int n0 = wn * 48 + ni * 16 + lk * 4;
                    int g = n0 >> 5, d0 = n0 & 31;
                    f4 v = acc[mi * 3 + ni];
                    f4 bb = *(const f4*)&bias[n0];
                    U4 u;
                    u.p2[0] = __builtin_amdgcn_cvt_pkrtz(v[0] + bb[0], v[1] + bb[1]);
                    u.p2[1] = __builtin_amdgcn_cvt_pkrtz(v[2] + bb[2], v[3] + bb[3]);
                    *(f16x4*)(outp + ((size_t)(b * NHEADS + g) * NPIX + p) * HD + d0) = u.v4;
                }
            }
        }
    }
}

// ---------------- MFMA neighborhood attention v3 (unchanged from R15) ----------------
#define NA2D_SMEM 68352          // 66560 (Vt) + 1764 (rpb) rounded

template<int K>
__device__ __forceinline__ void na2d_tile(
    const _Float16* __restrict__ qh, const _Float16* __restrict__ kh,
    const _Float16* __restrict__ vh, const float* __restrict__ rpb,
    _Float16* __restrict__ ah, char* smem, int b, int g_head, int hi, int ty, int tx)
{
    constexpr int NS = K / 2;
    constexpr int RW = 2 * K - 1;
    _Float16* Vt = (_Float16*)smem;
    float* rpbs = (float*)(smem + 66560);

    int t = threadIdx.x;
    size_t plane = (size_t)(b * NHEADS + g_head) * NPIX;
    int h0 = ty * 16, w0 = tx * 16;
    int rmin = min(max(h0 - NS, 0), HH - K);
    int rtop = min(max(h0 + 15 - NS, 0), HH - K);
    int rows_n = rtop + K - rmin;
    int cwin0 = min(max(w0 - NS, 0), WW - K);
    int ctop = min(max(w0 + 15 - NS, 0), WW - K);
    int cols_n = ctop + K - cwin0;

    for (int i = t; i < RW * RW; i += 512) rpbs[i] = rpb[(size_t)hi * RW * RW + i];

    int ntask = rows_n * 128;
    for (int idx = t; idx < ntask; idx += 512) {
        int row = idx >> 7;
        int key = (idx >> 2) & 31;
        int dc  = idx & 3;
        f16x8 vvv = {0,0,0,0,0,0,0,0};
        if (key < cols_n) {
            size_t pix = plane + (size_t)(rmin + row) * WW + (cwin0 + key);
            vvv = *(const f16x8*)&vh[pix * HD + dc * 8];
        }
        int m = 8 * ((key & 15) >> 2) + 4 * (key >> 4) + (key & 3);
        #pragma unroll
        for (int j = 0; j < 8; j++)
            Vt[row * 1280 + (dc * 8 + j) * LDK + m] = vvv[j];
    }
    __syncthreads();

    int lane = t & 63, wid = t >> 6;
    int lq = lane & 15, lg = lane >> 4;
    int wq = w0 + lq;
    int c0q = min(max(wq - NS, 0), WW - K);
    int klo = c0q - cwin0;
    int shiftc = cwin0 - wq + K - 1;
    f4 zf4 = {0.f, 0.f, 0.f, 0.f};

    #pragma unroll 1
    for (int qi = 0; qi < 2; qi++) {
        int qr = wid * 2 + qi;
        int h = h0 + qr;
        int r0q = min(max(h - NS, 0), HH - K);
        int row_base = r0q - rmin;
        f16x8 qf = *(const f16x8*)&qh[(plane + (size_t)h * WW + w0 + lq) * HD + lg * 8];
        f4 acc0 = zf4, acc1 = zf4;
        float lsum = 0.f;

        #pragma unroll 1
        for (int ki = 0; ki < K; ki++) {
            int row = row_base + ki;
            const _Float16* kgrow = kh + (plane + (size_t)(rmin + row) * WW + cwin0) * HD;
            f16x8 a0 = *(const f16x8*)&kgrow[(size_t)lq * HD + lg * 8];
            f16x8 a1 = *(const f16x8*)&kgrow[(size_t)(16 + lq) * HD + lg * 8];
            __builtin_amdgcn_s_setprio(1);
            f4 s0 = __builtin_amdgcn_mfma_f32_16x16x32_f16(a0, qf, zf4, 0, 0, 0);
            f4 s1 = __builtin_amdgcn_mfma_f32_16x16x32_f16(a1, qf, zf4, 0, 0, 0);
            __builtin_amdgcn_s_setprio(0);

            int rel_r = r0q + ki - h + K - 1;
            const float* rrow = rpbs + rel_r * RW;
            float pf[2][4];
            #pragma unroll
            for (int c = 0; c < 2; c++) {
                #pragma unroll
                for (int r = 0; r < 4; r++) {
                    int key_local = c * 16 + 4 * lg + r;
                    int rc = key_local + shiftc;
                    rc = min(max(rc, 0), RW - 1);
                    float biasv = rrow[rc];
                    bool valid = (unsigned)(key_local - klo) < (unsigned)K;
                    float sv = (c ? s1[r] : s0[r]) + biasv;
                    float pv = valid ? __expf(sv) : 0.f;
                    pf[c][r] = pv;
                    lsum += pv;
                }
            }
            union { g2 p[4]; f16x8 v; } P;
            P.p[0] = __builtin_amdgcn_cvt_pkrtz(pf[0][0], pf[0][1]);
            P.p[1] = __builtin_amdgcn_cvt_pkrtz(pf[0][2], pf[0][3]);
            P.p[2] = __builtin_amdgcn_cvt_pkrtz(pf[1][0], pf[1][1]);
            P.p[3] = __builtin_amdgcn_cvt_pkrtz(pf[1][2], pf[1][3]);

            const _Float16* vbase = &Vt[row * 1280 + lg * 8];
            f16x8 b0 = *(const f16x8*)&vbase[lq * LDK];
            f16x8 b1 = *(const f16x8*)&vbase[(16 + lq) * LDK];
            __builtin_amdgcn_s_setprio(1);
            acc0 = __builtin_amdgcn_mfma_f32_16x16x32_f16(P.v, b0, acc0, 0, 0, 0);
            acc1 = __builtin_amdgcn_mfma_f32_16x16x32_f16(P.v, b1, acc1, 0, 0, 0);
            __builtin_amdgcn_s_setprio(0);
        }

        lsum += __shfl_xor(lsum, 16);
        lsum += __shfl_xor(lsum, 32);
        float inv = 1.f / lsum;
        _Float16* obase = ah + (plane + (size_t)h * WW + w0) * HD;
        #pragma unroll
        for (int r = 0; r < 4; r++) {
            float ir = __shfl(inv, 4 * lg + r);
            obase[(4 * lg + r) * HD + lq]      = (_Float16)(acc0[r] * ir);
            obase[(4 * lg + r) * HD + lq + 16] = (_Float16)(acc1[r] * ir);
        }
    }
}

__global__ __launch_bounds__(512) void na2d_mfma(
    const _Float16* __restrict__ qh, const _Float16* __restrict__ kh,
    const _Float16* __restrict__ vh,
    const float* __restrict__ rpb0, const float* __restrict__ rpb1,
    const float* __restrict__ rpb2, _Float16* __restrict__ ah)
{
    extern __shared__ char smem[];
    int bid = blockIdx.x;
    int xcd = bid & 7;
    int i = bid >> 3;
    int phase = i >> 7;
    int j = i & 127;
    int lb = xcd * 128 + j;
    int bz = lb >> 6;
    int tile = lb & 63;
    int b = bz >> 1, hi = bz & 1;
    int ty = tile >> 3, tx = tile & 7;
    if (phase == 0)      na2d_tile<7>(qh, kh, vh, rpb0, ah, smem, b, 0 + hi, hi, ty, tx);
    else if (phase == 1) na2d_tile<9>(qh, kh, vh, rpb1, ah, smem, b, 2 + hi, hi, ty, tx);
    else                 na2d_tile<11>(qh, kh, vh, rpb2, ah, smem, b, 4 + hi, hi, ty, tx);
}

// ---------------- MFMA output projection (unchanged from R9-R15) ----------------
__global__ __launch_bounds__(512) void oproj_mfma(
    const _Float16* __restrict__ ah, const _Float16* __restrict__ woT,
    const float* __restrict__ bo, float* __restrict__ outp)
{
    int t = threadIdx.x;
    int m0 = blockIdx.x * 128;
    int b  = m0 / NPIX;
    int p0 = m0 % NPIX;

    int lane = t & 63;
    int wid  = t >> 6;
    int wm = wid & 1;
    int wn = wid >> 1;
    int lr = lane & 15;
    int lk = lane >> 4;

    f4 acc[4][3] = {};

    #pragma unroll
    for (int ks = 0; ks < 6; ks++) {
        const _Float16* abase = ah + (size_t)(b * NHEADS + ks) * NPIX * HD;
        f16x8 af[4], bf[3];
        #pragma unroll
        for (int mi = 0; mi < 4; mi++)
            af[mi] = *(const f16x8*)&abase[(size_t)(p0 + wm * 64 + mi * 16 + lr) * HD + lk * 8];
        #pragma unroll
        for (int ni = 0; ni < 3; ni++)
            bf[ni] = *(const f16x8*)&woT[(size_t)(wn * 48 + ni * 16 + lr) * 192 + ks * 32 + lk * 8];
        #pragma unroll
        for (int mi = 0; mi < 4; mi++)
            #pragma unroll
            for (int ni = 0; ni < 3; ni++)
                acc[mi][ni] = __builtin_amdgcn_mfma_f32_16x16x32_f16(af[mi], bf[ni], acc[mi][ni], 0, 0, 0);
    }

    #pragma unroll
    for (int ni = 0; ni < 3; ni++) {
        int n = wn * 48 + ni * 16 + lr;
        float bb = bo[n];
        float* obase = outp + ((size_t)b * 192 + n) * NPIX + p0 + wm * 64;
        #pragma unroll
        for (int mi = 0; mi < 4; mi++) {
            f4 v = acc[mi][ni];
            v[0] += bb; v[1] += bb; v[2] += bb; v[3] += bb;
            *(f4*)&obase[mi * 16 + lk * 4] = v;
        }
    }
}

extern "C" void kernel_launch(void* const* d_in, const int* in_sizes, int n_in,
                              void* d_out, int out_size, void* d_ws, size_t ws_size,
                              hipStream_t stream) {
    const float* x    = (const float*)d_in[0];
    const float* ctx  = (const float*)d_in[1];
    const float* Wq   = (const float*)d_in[2];
    const float* bq   = (const float*)d_in[3];
    const float* Wk   = (const float*)d_in[4];
    const float* bk   = (const float*)d_in[5];
    const float* Wv   = (const float*)d_in[6];
    const float* bv   = (const float*)d_in[7];
    const float* Wo   = (const float*)d_in[8];
    const float* bo   = (const float*)d_in[9];
    const float* rpb0 = (const float*)d_in[10];
    const float* rpb1 = (const float*)d_in[11];
    const float* rpb2 = (const float*)d_in[12];

    size_t N = (size_t)NB * NHEADS * NPIX * HD;   // 25,165,824 fp16 elements = 50.33MB
    _Float16* qh = (_Float16*)d_ws;
    _Float16* kh = qh + N;
    _Float16* vh = kh + N;
    _Float16* ah = vh + N;
    float* outp = (float*)d_out;

    // parking: WT fp16 in second half of d_out (dead until oproj); woT in qh (dead after na2d)
    _Float16* wt  = (_Float16*)d_out + N;
    _Float16* woT = qh;

    (void)hipFuncSetAttribute((const void*)na2d_mfma,
                              hipFuncAttributeMaxDynamicSharedMemorySize, NA2D_SMEM);

    prep_wt<<<216, 512, 0, stream>>>(Wq, Wk, Wv, wt);
    proj_mfma<<<2048, 512, 0, stream>>>(x, ctx, wt, bq, bk, bv, qh, kh, vh);
    na2d_mfma<<<3072, 512, NA2D_SMEM, stream>>>(qh, kh, vh, rpb0, rpb1, rpb2, ah);
    prep_wo<<<72, 512, 0, stream>>>(Wo, woT);
    oproj_mfma<<<1024, 512, 0, stream>>>(ah, woT, bo, outp);
}

// Round 17
// 235.903 us; speedup vs baseline: 1.0935x; 1.0052x over previous
//
#include <hip/hip_runtime.h>
#include <hip/hip_fp16.h>

#define HH 128
#define WW 128
#define NPIX (HH*WW)
#define NB 8
#define NHEADS 6
#define HD 32
#define SCALE 0.17677669529663687f
#define LOG2E 1.4426950408889634f
#define QSCALE (SCALE * LOG2E)

typedef _Float16 h2 __attribute__((ext_vector_type(2)));
typedef __fp16 g2 __attribute__((ext_vector_type(2)));
typedef _Float16 f16x4 __attribute__((ext_vector_type(4)));
typedef _Float16 f16x8 __attribute__((ext_vector_type(8)));
typedef float f4 __attribute__((ext_vector_type(4)));
typedef float f2 __attribute__((ext_vector_type(2)));

#if __has_builtin(__builtin_amdgcn_exp2f)
#define EXP2(x) __builtin_amdgcn_exp2f(x)
#else
#define EXP2(x) exp2f(x)
#endif

#define LDK 40    // na2d Vt padded stride
union U4 { g2 p2[2]; f16x4 v4; };

// ---------------- prep: WT[z][n][k] fp16 from W[z][k][n] fp32 ----------------
__global__ __launch_bounds__(512) void prep_wt(
    const float* __restrict__ Wq, const float* __restrict__ Wk,
    const float* __restrict__ Wv, _Float16* __restrict__ wt)
{
    int idx = blockIdx.x * 512 + threadIdx.x;      // 3*36864 total
    int mat = idx / 36864, rem = idx % 36864;
    int k = rem / 192, n = rem % 192;              // coalesced read over n
    const float* W = mat == 0 ? Wq : (mat == 1 ? Wk : Wv);
    wt[(size_t)mat * 36864 + (size_t)n * 192 + k] = (_Float16)W[(size_t)k * 192 + n];
}

__global__ __launch_bounds__(512) void prep_wo(
    const float* __restrict__ Wo, _Float16* __restrict__ woT)
{
    int idx = blockIdx.x * 512 + threadIdx.x;      // 36864
    int k = idx / 192, n = idx % 192;
    woT[(size_t)n * 192 + k] = (_Float16)Wo[(size_t)k * 192 + n];
}

// ---------------- MFMA projection v11 (as R16; q scaled by SCALE*log2e) ----------------
__global__ __launch_bounds__(512, 4) void proj_mfma(
    const float* __restrict__ x, const float* __restrict__ ctx,
    const _Float16* __restrict__ wt,
    const float* __restrict__ bq, const float* __restrict__ bk, const float* __restrict__ bv,
    _Float16* __restrict__ qh, _Float16* __restrict__ kh, _Float16* __restrict__ vh)
{
    int bid = blockIdx.x;             // 2048
    int xcd = bid & 7;
    int i = bid >> 3;                 // 0..255
    bool is_q = (i < 128);
    int xb = xcd * 128 + (is_q ? i : i - 128);

    const float* A = is_q ? x : ctx;

    __shared__ _Float16 Ts[128 * 192];   // 48KB; idx = pix*192 + (off ^ ((pix&7)<<3))

    int t = threadIdx.x;
    int m0 = xb * 128;
    int b  = m0 / NPIX;
    int p0 = m0 % NPIX;
    const float* Ab = A + (size_t)b * 192 * NPIX + p0;

    int lane = t & 63;
    int wid  = t >> 6;
    int wm = wid & 1;
    int wn = wid >> 1;
    int lq = lane & 15;
    int lk = lane >> 4;

    // ---- stage A tile: 12 x float4 NT loads/thread, swizzled 8B LDS writes ----
    {
        int pq = t & 31;
        int cg = t >> 5;
        int c_base = cg * 12;
        f4 ra[12];
        #pragma unroll
        for (int j = 0; j < 12; j++)
            ra[j] = __builtin_nontemporal_load((const f4*)&Ab[(size_t)(c_base + j) * NPIX + 4 * pq]);
        __builtin_amdgcn_sched_barrier(0);
        #pragma unroll
        for (int r = 0; r < 4; r++) {
            int pix = 4 * pq + r;
            int sw = (pix & 7) << 3;
            #pragma unroll
            for (int j4 = 0; j4 < 3; j4++) {
                int c0 = c_base + j4 * 4;
                U4 u;
                u.p2[0] = __builtin_amdgcn_cvt_pkrtz(ra[j4 * 4][r],     ra[j4 * 4 + 1][r]);
                u.p2[1] = __builtin_amdgcn_cvt_pkrtz(ra[j4 * 4 + 2][r], ra[j4 * 4 + 3][r]);
                *(f16x4*)&Ts[pix * 192 + (c0 ^ sw)] = u.v4;
            }
        }
    }
    __syncthreads();

    if (is_q) {
        const _Float16* WT = wt;
        f4 acc[12] = {};
        #pragma unroll
        for (int ks = 0; ks < 6; ks++) {
            f16x8 wf[3];
            #pragma unroll
            for (int ni = 0; ni < 3; ni++)
                wf[ni] = *(const f16x8*)&WT[(size_t)(wn * 48 + ni * 16 + lq) * 192 + ks * 32 + lk * 8];
            #pragma unroll
            for (int mi = 0; mi < 4; mi++) {
                int pix = wm * 64 + mi * 16 + lq;
                f16x8 pfr = *(const f16x8*)&Ts[pix * 192 + ((ks * 32 + lk * 8) ^ ((pix & 7) << 3))];
                __builtin_amdgcn_s_setprio(1);
                #pragma unroll
                for (int ni = 0; ni < 3; ni++)
                    acc[mi * 3 + ni] = __builtin_amdgcn_mfma_f32_16x16x32_f16(wf[ni], pfr, acc[mi * 3 + ni], 0, 0, 0);
                __builtin_amdgcn_s_setprio(0);
            }
        }
        __syncthreads();

        #pragma unroll
        for (int mi = 0; mi < 4; mi++) {
            int pix = wm * 64 + mi * 16 + lq;
            int sw = (pix & 7) << 3;
            #pragma unroll
            for (int ni = 0; ni < 3; ni++) {
                int n0 = wn * 48 + ni * 16 + lk * 4;
                f4 v = acc[mi * 3 + ni];
                f4 bb = *(const f4*)&bq[n0];
                U4 u;
                u.p2[0] = __builtin_amdgcn_cvt_pkrtz((v[0] + bb[0]) * QSCALE, (v[1] + bb[1]) * QSCALE);
                u.p2[1] = __builtin_amdgcn_cvt_pkrtz((v[2] + bb[2]) * QSCALE, (v[3] + bb[3]) * QSCALE);
                *(f16x4*)&Ts[pix * 192 + (n0 ^ sw)] = u.v4;
            }
        }
        __syncthreads();

        int p2 = t >> 2, qc = t & 3;
        int sw = (p2 & 7) << 3;
        #pragma unroll
        for (int g = 0; g < 6; g++) {
            f16x8 val = *(const f16x8*)&Ts[p2 * 192 + ((g * 32 + qc * 8) ^ sw)];
            *(f16x8*)(qh + ((size_t)(b * NHEADS + g) * NPIX + p0 + p2) * HD + qc * 8) = val;
        }
    } else {
        #pragma unroll
        for (int out = 0; out < 2; out++) {
            const _Float16* WT = wt + (size_t)(1 + out) * 36864;
            const float* bias = out == 0 ? bk : bv;
            _Float16* outp = out == 0 ? kh : vh;
            f4 acc[12] = {};
            #pragma unroll
            for (int ks = 0; ks < 6; ks++) {
                f16x8 wf[3];
                #pragma unroll
                for (int ni = 0; ni < 3; ni++)
                    wf[ni] = *(const f16x8*)&WT[(size_t)(wn * 48 + ni * 16 + lq) * 192 + ks * 32 + lk * 8];
                #pragma unroll
                for (int mi = 0; mi < 4; mi++) {
                    int pix = wm * 64 + mi * 16 + lq;
                    f16x8 pfr = *(const f16x8*)&Ts[pix * 192 + ((ks * 32 + lk * 8) ^ ((pix & 7) << 3))];
                    __builtin_amdgcn_s_setprio(1);
                    #pragma unroll
                    for (int ni = 0; ni < 3; ni++)
                        acc[mi * 3 + ni] = __builtin_amdgcn_mfma_f32_16x16x32_f16(wf[ni], pfr, acc[mi * 3 + ni], 0, 0, 0);
                    __builtin_amdgcn_s_setprio(0);
                }
            }
            #pragma unroll
            for (int mi = 0; mi < 4; mi++) {
                int p = p0 + wm * 64 + mi * 16 + lq;
                #pragma unroll
                for (int ni = 0; ni < 3; ni++) {
                    int n0 = wn * 48 + ni * 16 + lk * 4;
                    int g = n0 >> 5, d0 = n0 & 31;
                    f4 v = acc[mi * 3 + ni];
                    f4 bb = *(const f4*)&bias[n0];
                    U4 u;
                    u.p2[0] = __builtin_amdgcn_cvt_pkrtz(v[0] + bb[0], v[1] + bb[1]);
                    u.p2[1] = __builtin_amdgcn_cvt_pkrtz(v[2] + bb[2], v[3] + bb[3]);
                    *(f16x4*)(outp + ((size_t)(b * NHEADS + g) * NPIX + p) * HD + d0) = u.v4;
                }
            }
        }
    }
}

// ---------------- MFMA neighborhood attention v4: exp2-domain softmax + dot2 lsum ----------------
#define NA2D_SMEM 68352          // 66560 (Vt) + 1764 (rpb) rounded

template<int K>
__device__ __forceinline__ void na2d_tile(
    const _Float16* __restrict__ qh, const _Float16* __restrict__ kh,
    const _Float16* __restrict__ vh, const float* __restrict__ rpb,
    _Float16* __restrict__ ah, char* smem, int b, int g_head, int hi, int ty, int tx)
{
    constexpr int NS = K / 2;
    constexpr int RW = 2 * K - 1;
    _Float16* Vt = (_Float16*)smem;
    float* rpbs = (float*)(smem + 66560);

    int t = threadIdx.x;
    size_t plane = (size_t)(b * NHEADS + g_head) * NPIX;
    int h0 = ty * 16, w0 = tx * 16;
    int rmin = min(max(h0 - NS, 0), HH - K);
    int rtop = min(max(h0 + 15 - NS, 0), HH - K);
    int rows_n = rtop + K - rmin;
    int cwin0 = min(max(w0 - NS, 0), WW - K);
    int ctop = min(max(w0 + 15 - NS, 0), WW - K);
    int cols_n = ctop + K - cwin0;

    // stage rpb pre-scaled into log2 domain
    for (int i = t; i < RW * RW; i += 512) rpbs[i] = rpb[(size_t)hi * RW * RW + i] * LOG2E;

    int ntask = rows_n * 128;
    for (int idx = t; idx < ntask; idx += 512) {
        int row = idx >> 7;
        int key = (idx >> 2) & 31;
        int dc  = idx & 3;
        f16x8 vvv = {0,0,0,0,0,0,0,0};
        if (key < cols_n) {
            size_t pix = plane + (size_t)(rmin + row) * WW + (cwin0 + key);
            vvv = *(const f16x8*)&vh[pix * HD + dc * 8];
        }
        int m = 8 * ((key & 15) >> 2) + 4 * (key >> 4) + (key & 3);
        #pragma unroll
        for (int j = 0; j < 8; j++)
            Vt[row * 1280 + (dc * 8 + j) * LDK + m] = vvv[j];
    }
    __syncthreads();

    int lane = t & 63, wid = t >> 6;
    int lq = lane & 15, lg = lane >> 4;
    int wq = w0 + lq;
    int c0q = min(max(wq - NS, 0), WW - K);
    int klo = c0q - cwin0;
    int shiftc = cwin0 - wq + K - 1;
    f4 zf4 = {0.f, 0.f, 0.f, 0.f};

    // lane-invariant: key-column clamp + validity (hoisted out of qi/ki loops)
    int rcx[2][4];
    bool vld[2][4];
    #pragma unroll
    for (int c = 0; c < 2; c++) {
        #pragma unroll
        for (int r = 0; r < 4; r++) {
            int key_local = c * 16 + 4 * lg + r;
            rcx[c][r] = min(max(key_local + shiftc, 0), RW - 1);
            vld[c][r] = (unsigned)(key_local - klo) < (unsigned)K;
        }
    }
    h2 one2 = {(_Float16)1.f, (_Float16)1.f};

    #pragma unroll 1
    for (int qi = 0; qi < 2; qi++) {
        int qr = wid * 2 + qi;
        int h = h0 + qr;
        int r0q = min(max(h - NS, 0), HH - K);
        int row_base = r0q - rmin;
        f16x8 qf = *(const f16x8*)&qh[(plane + (size_t)h * WW + w0 + lq) * HD + lg * 8];
        f4 acc0 = zf4, acc1 = zf4;
        float lsum = 0.f;

        #pragma unroll 1
        for (int ki = 0; ki < K; ki++) {
            int row = row_base + ki;
            const _Float16* kgrow = kh + (plane + (size_t)(rmin + row) * WW + cwin0) * HD;
            f16x8 a0 = *(const f16x8*)&kgrow[(size_t)lq * HD + lg * 8];
            f16x8 a1 = *(const f16x8*)&kgrow[(size_t)(16 + lq) * HD + lg * 8];
            __builtin_amdgcn_s_setprio(1);
            f4 s0 = __builtin_amdgcn_mfma_f32_16x16x32_f16(a0, qf, zf4, 0, 0, 0);
            f4 s1 = __builtin_amdgcn_mfma_f32_16x16x32_f16(a1, qf, zf4, 0, 0, 0);
            __builtin_amdgcn_s_setprio(0);

            int rel_r = r0q + ki - h + K - 1;
            const float* rrow = rpbs + rel_r * RW;
            float pf[2][4];
            #pragma unroll
            for (int c = 0; c < 2; c++) {
                #pragma unroll
                for (int r = 0; r < 4; r++) {
                    float sv = (c ? s1[r] : s0[r]) + rrow[rcx[c][r]];
                    pf[c][r] = vld[c][r] ? EXP2(sv) : 0.f;
                }
            }
            union { g2 p[4]; h2 ph[4]; f16x8 v; } P;
            P.p[0] = __builtin_amdgcn_cvt_pkrtz(pf[0][0], pf[0][1]);
            P.p[1] = __builtin_amdgcn_cvt_pkrtz(pf[0][2], pf[0][3]);
            P.p[2] = __builtin_amdgcn_cvt_pkrtz(pf[1][0], pf[1][1]);
            P.p[3] = __builtin_amdgcn_cvt_pkrtz(pf[1][2], pf[1][3]);
            lsum = __builtin_amdgcn_fdot2(P.ph[0], one2, lsum, false);
            lsum = __builtin_amdgcn_fdot2(P.ph[1], one2, lsum, false);
            lsum = __builtin_amdgcn_fdot2(P.ph[2], one2, lsum, false);
            lsum = __builtin_amdgcn_fdot2(P.ph[3], one2, lsum, false);

            const _Float16* vbase = &Vt[row * 1280 + lg * 8];
            f16x8 b0 = *(const f16x8*)&vbase[lq * LDK];
            f16x8 b1 = *(const f16x8*)&vbase[(16 + lq) * LDK];
            __builtin_amdgcn_s_setprio(1);
            acc0 = __builtin_amdgcn_mfma_f32_16x16x32_f16(P.v, b0, acc0, 0, 0, 0);
            acc1 = __builtin_amdgcn_mfma_f32_16x16x32_f16(P.v, b1, acc1, 0, 0, 0);
            __builtin_amdgcn_s_setprio(0);
        }

        lsum += __shfl_xor(lsum, 16);
        lsum += __shfl_xor(lsum, 32);
        float inv = 1.f / lsum;
        _Float16* obase = ah + (plane + (size_t)h * WW + w0) * HD;
        #pragma unroll
        for (int r = 0; r < 4; r++) {
            float ir = __shfl(inv, 4 * lg + r);
            obase[(4 * lg + r) * HD + lq]      = (_Float16)(acc0[r] * ir);
            obase[(4 * lg + r) * HD + lq + 16] = (_Float16)(acc1[r] * ir);
        }
    }
}

__global__ __launch_bounds__(512) void na2d_mfma(
    const _Float16* __restrict__ qh, const _Float16* __restrict__ kh,
    const _Float16* __restrict__ vh,
    const float* __restrict__ rpb0, const float* __restrict__ rpb1,
    const float* __restrict__ rpb2, _Float16* __restrict__ ah)
{
    extern __shared__ char smem[];
    int bid = blockIdx.x;
    int xcd = bid & 7;
    int i = bid >> 3;
    int phase = i >> 7;
    int j = i & 127;
    int lb = xcd * 128 + j;
    int bz = lb >> 6;
    int tile = lb & 63;
    int b = bz >> 1, hi = bz & 1;
    int ty = tile >> 3, tx = tile & 7;
    if (phase == 0)      na2d_tile<7>(qh, kh, vh, rpb0, ah, smem, b, 0 + hi, hi, ty, tx);
    else if (phase == 1) na2d_tile<9>(qh, kh, vh, rpb1, ah, smem, b, 2 + hi, hi, ty, tx);
    else                 na2d_tile<11>(qh, kh, vh, rpb2, ah, smem, b, 4 + hi, hi, ty, tx);
}

// ---------------- MFMA output projection (unchanged from R9-R16) ----------------
__global__ __launch_bounds__(512) void oproj_mfma(
    const _Float16* __restrict__ ah, const _Float16* __restrict__ woT,
    const float* __restrict__ bo, float* __restrict__ outp)
{
    int t = threadIdx.x;
    int m0 = blockIdx.x * 128;
    int b  = m0 / NPIX;
    int p0 = m0 % NPIX;

    int lane = t & 63;
    int wid  = t >> 6;
    int wm = wid & 1;
    int wn = wid >> 1;
    int lr = lane & 15;
    int lk = lane >> 4;

    f4 acc[4][3] = {};

    #pragma unroll
    for (int ks = 0; ks < 6; ks++) {
        const _Float16* abase = ah + (size_t)(b * NHEADS + ks) * NPIX * HD;
        f16x8 af[4], bf[3];
        #pragma unroll
        for (int mi = 0; mi < 4; mi++)
            af[mi] = *(const f16x8*)&abase[(size_t)(p0 + wm * 64 + mi * 16 + lr) * HD + lk * 8];
        #pragma unroll
        for (int ni = 0; ni < 3; ni++)
            bf[ni] = *(const f16x8*)&woT[(size_t)(wn * 48 + ni * 16 + lr) * 192 + ks * 32 + lk * 8];
        #pragma unroll
        for (int mi = 0; mi < 4; mi++)
            #pragma unroll
            for (int ni = 0; ni < 3; ni++)
                acc[mi][ni] = __builtin_amdgcn_mfma_f32_16x16x32_f16(af[mi], bf[ni], acc[mi][ni], 0, 0, 0);
    }

    #pragma unroll
    for (int ni = 0; ni < 3; ni++) {
        int n = wn * 48 + ni * 16 + lr;
        float bb = bo[n];
        float* obase = outp + ((size_t)b * 192 + n) * NPIX + p0 + wm * 64;
        #pragma unroll
        for (int mi = 0; mi < 4; mi++) {
            f4 v = acc[mi][ni];
            v[0] += bb; v[1] += bb; v[2] += bb; v[3] += bb;
            *(f4*)&obase[mi * 16 + lk * 4] = v;
        }
    }
}

extern "C" void kernel_launch(void* const* d_in, const int* in_sizes, int n_in,
                              void* d_out, int out_size, void* d_ws, size_t ws_size,
                              hipStream_t stream) {
    const float* x    = (const float*)d_in[0];
    const float* ctx  = (const float*)d_in[1];
    const float* Wq   = (const float*)d_in[2];
    const float* bq   = (const float*)d_in[3];
    const float* Wk   = (const float*)d_in[4];
    const float* bk   = (const float*)d_in[5];
    const float* Wv   = (const float*)d_in[6];
    const float* bv   = (const float*)d_in[7];
    const float* Wo   = (const float*)d_in[8];
    const float* bo   = (const float*)d_in[9];
    const float* rpb0 = (const float*)d_in[10];
    const float* rpb1 = (const float*)d_in[11];
    const float* rpb2 = (const float*)d_in[12];

    size_t N = (size_t)NB * NHEADS * NPIX * HD;   // 25,165,824 fp16 elements = 50.33MB
    _Float16* qh = (_Float16*)d_ws;
    _Float16* kh = qh + N;
    _Float16* vh = kh + N;
    _Float16* ah = vh + N;
    float* outp = (float*)d_out;

    // parking: WT fp16 in second half of d_out (dead until oproj); woT in qh (dead after na2d)
    _Float16* wt  = (_Float16*)d_out + N;
    _Float16* woT = qh;

    (void)hipFuncSetAttribute((const void*)na2d_mfma,
                              hipFuncAttributeMaxDynamicSharedMemorySize, NA2D_SMEM);

    prep_wt<<<216, 512, 0, stream>>>(Wq, Wk, Wv, wt);
    proj_mfma<<<2048, 512, 0, stream>>>(x, ctx, wt, bq, bk, bv, qh, kh, vh);
    na2d_mfma<<<3072, 512, NA2D_SMEM, stream>>>(qh, kh, vh, rpb0, rpb1, rpb2, ah);
    prep_wo<<<72, 512, 0, stream>>>(Wo, woT);
    oproj_mfma<<<1024, 512, 0, stream>>>(ah, woT, bo, outp);
}